// Round 5
// baseline (3979.672 us; speedup 1.0000x reference)
//
#include <hip/hip_runtime.h>
#include <hip/hip_bf16.h>

// B=64, S=2048, WIN=50, E=128, H=256, G=4H=1024.
#define B_ 64
#define S_ 2048
#define W_ 50
#define E_ 128
#define H_ 256
#define G_ 1024

typedef unsigned short u16;
typedef unsigned int u32;
typedef unsigned char u8;
typedef unsigned int v4u __attribute__((ext_vector_type(4)));
typedef __attribute__((ext_vector_type(8))) short short8;   // bf16x8 MFMA frag
typedef __attribute__((ext_vector_type(4))) float f32x4;    // MFMA f32 acc
typedef __attribute__((ext_vector_type(4))) int i32x4;      // MFMA i32 acc

// Module-global scratch (BSS; d_ws untrusted).
__device__ int g_mode;                          // 0 = bf16 buffers, 1 = fp32 buffers
__device__ u16 g_WA[E_ * G_];                   // Wih in MFMA A-frag order (bf16) [r3-validated]
__device__ float g_bias[G_];                    // bih+bhh, gate-interleaved c = 4u+q
__device__ u32 g_Wi8[G_ * 64];                  // [u][j][g]: pack4(Whh col c=4u+g, k=4j..4j+3)
__device__ u32 g_WqA[G_ * 64];                  // Whh i8 in MFMA A-frag order
__device__ float g_wscale[G_];                  // per-column dequant: max|W[:,c]| /(127*127), c=4u+g
__device__ u16 g_xg[(size_t)B_ * S_ * G_];      // [b][s][1024] bf16, biases folded (validated)
__device__ float g_hs[(size_t)B_ * S_ * H_];    // [b][s][u] fp32 hidden states (for output head)

__device__ __forceinline__ float b2f(u16 u) {
    union { u32 i; float f; } v;
    v.i = ((u32)u) << 16;
    return v.f;
}
__device__ __forceinline__ u16 f2b(float f) {
    __hip_bfloat16 h = __float2bfloat16(f);
    return *reinterpret_cast<u16*>(&h);
}
__device__ __forceinline__ float ldin(int mode, const void* p, size_t i) {
    return mode ? ((const float*)p)[i] : b2f(((const u16*)p)[i]);
}
__device__ __forceinline__ float clamp30(float x) {
    return fminf(fmaxf(x, -30.0f), 30.0f);
}
__device__ __forceinline__ float sigmoidf_(float x) { return 1.0f / (1.0f + __expf(-x)); }
__device__ __forceinline__ float tanhf_(float x) {
    float e = __expf(2.0f * x);
    return 1.0f - 2.0f / (e + 1.0f);
}

// ---------- K0: dtype sniffer (validated) ----------
__global__ void sniff_kernel(const u16* __restrict__ wemb) {
    int sane = 0;
    for (int i = 0; i < 2048; ++i) {
        int ex = (wemb[i] >> 7) & 0xFF;
        if (ex == 0 || (ex >= 96 && ex <= 143)) ++sane;
    }
    g_mode = (sane >= 1900) ? 0 : 1;
}

// ---------- K0b: Wih -> MFMA A-fragment order (r3-validated) ----------
__global__ __launch_bounds__(256) void prep_wa(const void* __restrict__ src) {
    const int mode = g_mode;
    int i = blockIdx.x * 256 + threadIdx.x;          // dst flat index, 0..131071
    int j = i & 7, l = (i >> 3) & 63, ks = (i >> 9) & 3, ct = i >> 11;
    int c = ct * 16 + (l & 15);
    int e = ks * 32 + (l >> 4) * 8 + j;
    int row = ((c & 3) << 8) + (c >> 2);
    g_WA[i] = f2b(ldin(mode, src, (size_t)row * E_ + e));
}

// ---------- K0c: Whh -> int8, unit-major quad layout [u][j][g]; + gate biases ----------
__global__ __launch_bounds__(256) void prep_wi8(const void* __restrict__ src,
                                                const void* __restrict__ bih,
                                                const void* __restrict__ bhh) {
    const int mode = g_mode;
    int c = blockIdx.x * 256 + threadIdx.x;          // c = 4u+g, 0..1023
    int row = ((c & 3) << 8) + (c >> 2);             // gate*256 + unit (validated)
    g_bias[c] = ldin(mode, bih, row) + ldin(mode, bhh, row);
    const size_t base = (size_t)row * H_;
    float m = 0.0f;
    for (int k = 0; k < H_; ++k) m = fmaxf(m, fabsf(ldin(mode, src, base + k)));
    float inv = (m > 0.0f) ? 127.0f / m : 0.0f;
    g_wscale[c] = m / (127.0f * 127.0f);             // w-scale * h-scale(1/127)
    for (int j = 0; j < 64; ++j) {
        u32 pk = 0;
#pragma unroll
        for (int i = 0; i < 4; ++i) {
            int q = (int)rintf(ldin(mode, src, base + 4 * j + i) * inv);
            q = max(-127, min(127, q));
            pk |= ((u32)(q & 0xff)) << (8 * i);
        }
        g_Wi8[(size_t)(c >> 2) * 256 + j * 4 + (c & 3)] = pk;
    }
}

// ---------- K0d: g_Wi8 -> MFMA i8 A-frag order (pure dword gather) ----------
// Consumed as: frag p = mt*8+kt of wave w, lane l = dwords ((w*64+l)*64 + p)*2 + {0,1}.
// A element (row, k): row = w*128 + mt*16 + (l&15); k = kt*32 + (l>>4)*8 + j, j=0..7.
// Source dword for bytes k0..k0+3 of column c: g_Wi8[(c>>2)*256 + (k0>>2)*4 + (c&3)].
__global__ __launch_bounds__(256) void prep_wqa() {
    int i = blockIdx.x * 256 + threadIdx.x;          // dword idx 0..65535
    int d = i & 1, r = i >> 1;
    int kt = r & 7, mt = (r >> 3) & 7, l = (r >> 6) & 63, w = r >> 12;
    int c = w * 128 + mt * 16 + (l & 15);
    int k0 = kt * 32 + ((l >> 4) << 3) + d * 4;
    g_WqA[i] = g_Wi8[(size_t)(c >> 2) * 256 + (k0 >> 2) * 4 + (c & 3)];
}

// ---------- K1: fused embedding (VALU) + input projection (MFMA, r3-validated) ----------
__global__ __launch_bounds__(256) void xg_mfma(const void* __restrict__ pw,
                                               const void* __restrict__ Wemb,
                                               const void* __restrict__ bemb) {
    const int mode = g_mode;
    const int t = threadIdx.x;
    const int m0 = blockIdx.x * 16;
    __shared__ float pw16[16][W_ + 2];
    __shared__ float Wl[E_ * 51];
    __shared__ __align__(16) u16 embL[16][136];

    for (int i = t; i < E_ * W_; i += 256) {
        int e = i / W_, w = i - e * W_;
        Wl[e * 51 + w] = ldin(mode, Wemb, i);
    }
    for (int i = t; i < 16 * W_; i += 256) {
        int r = i / W_, w = i - r * W_;
        pw16[r][w] = ldin(mode, pw, (size_t)(m0 + r) * W_ + w);
    }
    __syncthreads();

#pragma unroll
    for (int i = 0; i < 8; ++i) {
        int idx = i * 256 + t;
        int r = idx >> 7, e = idx & 127;
        float a = ldin(mode, bemb, e);
        const float* wr = &Wl[e * 51];
#pragma unroll
        for (int w = 0; w < W_; ++w) a = fmaf(pw16[r][w], wr[w], a);
        embL[r][e] = f2b(fmaxf(a, 0.0f));
    }
    __syncthreads();

    const int l = t & 63;
    const int wv = t >> 6;
    short8 Bf0 = *(const short8*)&embL[l & 15][0 * 32 + (l >> 4) * 8];
    short8 Bf1 = *(const short8*)&embL[l & 15][1 * 32 + (l >> 4) * 8];
    short8 Bf2 = *(const short8*)&embL[l & 15][2 * 32 + (l >> 4) * 8];
    short8 Bf3 = *(const short8*)&embL[l & 15][3 * 32 + (l >> 4) * 8];
    const short8* wa = (const short8*)g_WA;
    const int m = m0 + (l & 15);
#pragma unroll
    for (int tt = 0; tt < 16; ++tt) {
        const int ct = wv * 16 + tt;
        const int cbase = ct * 16;
        const float4 bv = *(const float4*)(g_bias + cbase + 4 * (l >> 4));
        f32x4 acc = {bv.x, bv.y, bv.z, bv.w};
        acc = __builtin_amdgcn_mfma_f32_16x16x32_bf16(wa[(ct * 4 + 0) * 64 + l], Bf0, acc, 0, 0, 0);
        acc = __builtin_amdgcn_mfma_f32_16x16x32_bf16(wa[(ct * 4 + 1) * 64 + l], Bf1, acc, 0, 0, 0);
        acc = __builtin_amdgcn_mfma_f32_16x16x32_bf16(wa[(ct * 4 + 2) * 64 + l], Bf2, acc, 0, 0, 0);
        acc = __builtin_amdgcn_mfma_f32_16x16x32_bf16(wa[(ct * 4 + 3) * 64 + l], Bf3, acc, 0, 0, 0);
        u32 p0 = (u32)f2b(acc[0]) | ((u32)f2b(acc[1]) << 16);
        u32 p1 = (u32)f2b(acc[2]) | ((u32)f2b(acc[3]) << 16);
        uint2 pv; pv.x = p0; pv.y = p1;
        *(uint2*)(g_xg + (size_t)m * G_ + cbase + 4 * (l >> 4)) = pv;
    }
}

// ---------- K2: recurrence via MFMA i8 (512 thr, 8 waves, 2 waves/EU) ----------
// Per wave: M=128 gate rows, 8 m-tiles x 8 k-tiles of mfma_i32_16x16x32_i8.
// B = h-bytes broadcast from LDS (N=1; cols 1-15 garbage, ignored). D col 0 lives
// on lanes {0,16,32,48}; bounced through LDS (within-wave, lgkmcnt only) so lanes
// 0..31 each own one unit (4 gates). Integer math identical to the dot4 version.
// Loader uses NAMED scalar v4u regs (r0-r3-validated pattern; array-element asm
// outputs risked scratch allocation).
#define MFMAI8(a, b, c) __builtin_amdgcn_mfma_i32_16x16x32_i8((a), (b), (c), 0, 0, 0)
#define MKQ(lo, hi) ((long)((((unsigned long long)(hi)) << 32) | (lo)))
#define MKL(v) ((long)((((unsigned long long)(v).y) << 32) | (v).x))

__global__ __launch_bounds__(512)
__attribute__((amdgpu_waves_per_eu(2, 2)))
void lstm_mfma(const void* __restrict__ h0, const void* __restrict__ c0) {
    const int mode = g_mode;
    const int t = threadIdx.x;
    const int b = blockIdx.x;
    const int w = t >> 6;
    const int l = t & 63;
    const int lg8 = (l >> 4) << 3;       // B-frag k-byte offset
    const int lg4 = (l >> 4) << 2;       // D row-quad offset
    const bool lq0 = ((l & 15) == 0);
    const int u = w * 32 + (l & 31);     // unit owned by this lane (l<32 active)

    __shared__ __align__(16) u32 h8[2][64];   // double-buffered h (i8), 2x256 B
    __shared__ __align__(16) int gb[8][128];  // per-wave gate bounce (i32), 4 KB

    // --- 32 A-frag quads (128 dwords) into NAMED v4u regs via asm ---
    v4u Q00, Q01, Q02, Q03, Q04, Q05, Q06, Q07, Q08, Q09, Q10, Q11, Q12, Q13, Q14, Q15;
    v4u Q16, Q17, Q18, Q19, Q20, Q21, Q22, Q23, Q24, Q25, Q26, Q27, Q28, Q29, Q30, Q31;
    {
        const u32* wp = g_WqA + (size_t)t * 128;
        asm volatile(
            "global_load_dwordx4 %0, %16, off\n\t"
            "global_load_dwordx4 %1, %16, off offset:16\n\t"
            "global_load_dwordx4 %2, %16, off offset:32\n\t"
            "global_load_dwordx4 %3, %16, off offset:48\n\t"
            "global_load_dwordx4 %4, %16, off offset:64\n\t"
            "global_load_dwordx4 %5, %16, off offset:80\n\t"
            "global_load_dwordx4 %6, %16, off offset:96\n\t"
            "global_load_dwordx4 %7, %16, off offset:112\n\t"
            "global_load_dwordx4 %8, %16, off offset:128\n\t"
            "global_load_dwordx4 %9, %16, off offset:144\n\t"
            "global_load_dwordx4 %10, %16, off offset:160\n\t"
            "global_load_dwordx4 %11, %16, off offset:176\n\t"
            "global_load_dwordx4 %12, %16, off offset:192\n\t"
            "global_load_dwordx4 %13, %16, off offset:208\n\t"
            "global_load_dwordx4 %14, %16, off offset:224\n\t"
            "global_load_dwordx4 %15, %16, off offset:240\n\t"
            "s_waitcnt vmcnt(0)"
            : "=&v"(Q00), "=&v"(Q01), "=&v"(Q02), "=&v"(Q03),
              "=&v"(Q04), "=&v"(Q05), "=&v"(Q06), "=&v"(Q07),
              "=&v"(Q08), "=&v"(Q09), "=&v"(Q10), "=&v"(Q11),
              "=&v"(Q12), "=&v"(Q13), "=&v"(Q14), "=&v"(Q15)
            : "v"(wp));
        asm volatile(
            "global_load_dwordx4 %0, %16, off offset:256\n\t"
            "global_load_dwordx4 %1, %16, off offset:272\n\t"
            "global_load_dwordx4 %2, %16, off offset:288\n\t"
            "global_load_dwordx4 %3, %16, off offset:304\n\t"
            "global_load_dwordx4 %4, %16, off offset:320\n\t"
            "global_load_dwordx4 %5, %16, off offset:336\n\t"
            "global_load_dwordx4 %6, %16, off offset:352\n\t"
            "global_load_dwordx4 %7, %16, off offset:368\n\t"
            "global_load_dwordx4 %8, %16, off offset:384\n\t"
            "global_load_dwordx4 %9, %16, off offset:400\n\t"
            "global_load_dwordx4 %10, %16, off offset:416\n\t"
            "global_load_dwordx4 %11, %16, off offset:432\n\t"
            "global_load_dwordx4 %12, %16, off offset:448\n\t"
            "global_load_dwordx4 %13, %16, off offset:464\n\t"
            "global_load_dwordx4 %14, %16, off offset:480\n\t"
            "global_load_dwordx4 %15, %16, off offset:496\n\t"
            "s_waitcnt vmcnt(0)"
            : "=&v"(Q16), "=&v"(Q17), "=&v"(Q18), "=&v"(Q19),
              "=&v"(Q20), "=&v"(Q21), "=&v"(Q22), "=&v"(Q23),
              "=&v"(Q24), "=&v"(Q25), "=&v"(Q26), "=&v"(Q27),
              "=&v"(Q28), "=&v"(Q29), "=&v"(Q30), "=&v"(Q31)
            : "v"(wp));
    }

    const float4 wsf4 = *(const float4*)(g_wscale + 4 * u);   // hoisted dequant scales
    const u16* xp = g_xg + (size_t)b * S_ * G_ + 4 * u;
    float* hsp = g_hs + (size_t)b * S_ * H_ + u;
    float c_reg = 0.0f;
    ushort4 xqA, xqB;
    xqA.x = xqA.y = xqA.z = xqA.w = 0;
    xqB = xqA;
    if (l < 32) {
        c_reg = ldin(mode, c0, (size_t)b * H_ + u);
        float hh = ldin(mode, h0, (size_t)b * H_ + u);
        int q = (int)rintf(fminf(fmaxf(hh, -1.0f), 1.0f) * 127.0f) & 0xff;
        ((u8*)&h8[0][0])[u] = (u8)q;
        xqA = *(const ushort4*)(xp);
        xqB = *(const ushort4*)(xp + G_);
    }
    asm volatile("s_waitcnt lgkmcnt(0)\n\t"
                 "s_barrier" ::: "memory");

#define MTROW(mt, QA, QB, QC, QD, B0, B1, B2, B3, B4, B5, B6, B7)             \
    {                                                                         \
        i32x4 acc = {0, 0, 0, 0};                                             \
        acc = MFMAI8(MKQ(QA.x, QA.y), B0, acc);                               \
        acc = MFMAI8(MKQ(QA.z, QA.w), B1, acc);                               \
        acc = MFMAI8(MKQ(QB.x, QB.y), B2, acc);                               \
        acc = MFMAI8(MKQ(QB.z, QB.w), B3, acc);                               \
        acc = MFMAI8(MKQ(QC.x, QC.y), B4, acc);                               \
        acc = MFMAI8(MKQ(QC.z, QC.w), B5, acc);                               \
        acc = MFMAI8(MKQ(QD.x, QD.y), B6, acc);                               \
        acc = MFMAI8(MKQ(QD.z, QD.w), B7, acc);                               \
        if (lq0) *(i32x4*)&gb[w][(mt) * 16 + lg4] = acc;                      \
    }

#define STEP(S, XQ, SN)                                                       \
    {                                                                         \
        const u8* hb = (const u8*)&h8[(S) & 1][0];                            \
        uint2 bf0 = *(const uint2*)(hb + 0 * 32 + lg8);                       \
        uint2 bf1 = *(const uint2*)(hb + 1 * 32 + lg8);                       \
        uint2 bf2 = *(const uint2*)(hb + 2 * 32 + lg8);                       \
        uint2 bf3 = *(const uint2*)(hb + 3 * 32 + lg8);                       \
        uint2 bf4 = *(const uint2*)(hb + 4 * 32 + lg8);                       \
        uint2 bf5 = *(const uint2*)(hb + 5 * 32 + lg8);                       \
        uint2 bf6 = *(const uint2*)(hb + 6 * 32 + lg8);                       \
        uint2 bf7 = *(const uint2*)(hb + 7 * 32 + lg8);                       \
        const long Bl0 = MKL(bf0), Bl1 = MKL(bf1), Bl2 = MKL(bf2);            \
        const long Bl3 = MKL(bf3), Bl4 = MKL(bf4), Bl5 = MKL(bf5);            \
        const long Bl6 = MKL(bf6), Bl7 = MKL(bf7);                            \
        MTROW(0, Q00, Q01, Q02, Q03, Bl0, Bl1, Bl2, Bl3, Bl4, Bl5, Bl6, Bl7)  \
        MTROW(1, Q04, Q05, Q06, Q07, Bl0, Bl1, Bl2, Bl3, Bl4, Bl5, Bl6, Bl7)  \
        MTROW(2, Q08, Q09, Q10, Q11, Bl0, Bl1, Bl2, Bl3, Bl4, Bl5, Bl6, Bl7)  \
        MTROW(3, Q12, Q13, Q14, Q15, Bl0, Bl1, Bl2, Bl3, Bl4, Bl5, Bl6, Bl7)  \
        MTROW(4, Q16, Q17, Q18, Q19, Bl0, Bl1, Bl2, Bl3, Bl4, Bl5, Bl6, Bl7)  \
        MTROW(5, Q20, Q21, Q22, Q23, Bl0, Bl1, Bl2, Bl3, Bl4, Bl5, Bl6, Bl7)  \
        MTROW(6, Q24, Q25, Q26, Q27, Bl0, Bl1, Bl2, Bl3, Bl4, Bl5, Bl6, Bl7)  \
        MTROW(7, Q28, Q29, Q30, Q31, Bl0, Bl1, Bl2, Bl3, Bl4, Bl5, Bl6, Bl7)  \
        asm volatile("s_waitcnt lgkmcnt(0)" ::: "memory");                    \
        if (l < 32) {                                                         \
            const i32x4 gv = *(const i32x4*)&gb[w][4 * (l & 31)];             \
            const ushort4 xv = XQ;                                            \
            XQ = *(const ushort4*)(xp + (size_t)(SN) * G_);                   \
            float gi = (float)gv.x * wsf4.x + b2f(xv.x);                      \
            float gf = (float)gv.y * wsf4.y + b2f(xv.y);                      \
            float gg = (float)gv.z * wsf4.z + b2f(xv.z);                      \
            float go = (float)gv.w * wsf4.w + b2f(xv.w);                      \
            float ii = sigmoidf_(gi);                                         \
            float ff = sigmoidf_(gf);                                         \
            float gt = tanhf_(gg);                                            \
            float oo = sigmoidf_(go);                                         \
            c_reg = fmaf(ff, c_reg, ii * gt);                                 \
            float hv = oo * tanhf_(c_reg);                                    \
            ((u8*)&h8[((S) + 1) & 1][0])[u] =                                 \
                (u8)((int)rintf(hv * 127.0f) & 0xff);                         \
            hsp[(size_t)(S) * H_] = hv;                                       \
        }                                                                     \
        asm volatile("s_waitcnt lgkmcnt(0)\n\t"                               \
                     "s_barrier" ::: "memory");                               \
    }

    for (int s0 = 0; s0 < S_; s0 += 2) {
        STEP(s0,     xqA, (s0 + 2 < S_) ? s0 + 2 : s0)
        STEP(s0 + 1, xqB, (s0 + 3 < S_) ? s0 + 3 : s0 + 1)
    }
#undef STEP
#undef MTROW
}

// ---------- K3: output head — one wave per (s,b), fp32 h ----------
__global__ __launch_bounds__(256) void head_kernel(const void* __restrict__ Wout,
                                                   const void* __restrict__ bout,
                                                   void* __restrict__ yv) {
    const int mode = g_mode;
    const int t = threadIdx.x;
    const int idx = blockIdx.x * 4 + (t >> 6);   // (s,b) pair
    const int l = t & 63;
    const int s = idx >> 6, b = idx & 63;
    const float* hb = g_hs + ((size_t)b * S_ + s) * H_ + 4 * l;
    float4 hv = *(const float4*)hb;
    float p = hv.x * ldin(mode, Wout, 4 * l + 0)
            + hv.y * ldin(mode, Wout, 4 * l + 1)
            + hv.z * ldin(mode, Wout, 4 * l + 2)
            + hv.w * ldin(mode, Wout, 4 * l + 3);
#pragma unroll
    for (int off = 32; off > 0; off >>= 1) p += __shfl_down(p, off, 64);
    if (l == 0) {
        float yf = sigmoidf_(clamp30(p + ldin(mode, bout, 0)));
        if (mode) ((float*)yv)[(size_t)s * B_ + b] = yf;
        else      ((u16*)yv)[(size_t)s * B_ + b] = f2b(yf);
    }
}

extern "C" void kernel_launch(void* const* d_in, const int* in_sizes, int n_in,
                              void* d_out, int out_size, void* d_ws, size_t ws_size,
                              hipStream_t stream) {
    const void* pw   = d_in[0];   // [B,S,50]
    const void* Wemb = d_in[1];   // [E,50]
    const void* bemb = d_in[2];   // [E]
    const void* Wih  = d_in[3];   // [G,E]
    const void* Whh  = d_in[4];   // [G,H]
    const void* bih  = d_in[5];   // [G]
    const void* bhh  = d_in[6];   // [G]
    const void* Wout = d_in[7];   // [1,H]
    const void* bout = d_in[8];   // [1]
    const void* h0   = d_in[9];   // [B,H]
    const void* c0   = d_in[10];  // [B,H]
    void* y = d_out;              // [S,B]
    (void)d_ws; (void)ws_size;

    sniff_kernel<<<1, 1, 0, stream>>>((const u16*)Wemb);
    prep_wa<<<(E_ * G_) / 256, 256, 0, stream>>>(Wih);
    prep_wi8<<<G_ / 256, 256, 0, stream>>>(Whh, bih, bhh);
    prep_wqa<<<(G_ * 64) / 256, 256, 0, stream>>>();
    xg_mfma<<<(B_ * S_) / 16, 256, 0, stream>>>(pw, Wemb, bemb);
    lstm_mfma<<<B_, 512, 0, stream>>>(h0, c0);
    head_kernel<<<(S_ * B_) / 4, 256, 0, stream>>>(Wout, bout, y);
}

// Round 6
// 3587.289 us; speedup vs baseline: 1.1094x; 1.1094x over previous
//
#include <hip/hip_runtime.h>
#include <hip/hip_bf16.h>

// B=64, S=2048, WIN=50, E=128, H=256, G=4H=1024.
#define B_ 64
#define S_ 2048
#define W_ 50
#define E_ 128
#define H_ 256
#define G_ 1024

typedef unsigned short u16;
typedef unsigned int u32;
typedef unsigned char u8;
typedef unsigned int v4u __attribute__((ext_vector_type(4)));
typedef __attribute__((ext_vector_type(8))) short short8;   // bf16x8 MFMA frag
typedef __attribute__((ext_vector_type(4))) float f32x4;    // MFMA f32 acc
typedef __attribute__((ext_vector_type(4))) int i32x4;      // MFMA i32 acc

// Module-global scratch (BSS; d_ws untrusted).
__device__ int g_mode;                          // 0 = bf16 buffers, 1 = fp32 buffers
__device__ u16 g_WA[E_ * G_];                   // Wih in MFMA A-frag order (bf16) [r3-validated]
__device__ float g_bias[G_];                    // bih+bhh, gate-interleaved c = 4u+q
__device__ u32 g_Wi8[G_ * 64];                  // [u][j][g]: pack4(Whh col c=4u+g, k=4j..4j+3)
__device__ u32 g_WqA[G_ * 64];                  // Whh i8 in MFMA A-frag order [r5-validated]
__device__ float g_wscale[G_];                  // per-column dequant: max|W[:,c]| /(127*127), c=4u+g
__device__ u16 g_xg[(size_t)B_ * S_ * G_];      // [b][s][1024] bf16, biases folded (validated)
__device__ float g_hs[(size_t)B_ * S_ * H_];    // [b][s][u] fp32 hidden states (for output head)

__device__ __forceinline__ float b2f(u16 u) {
    union { u32 i; float f; } v;
    v.i = ((u32)u) << 16;
    return v.f;
}
__device__ __forceinline__ u16 f2b(float f) {
    __hip_bfloat16 h = __float2bfloat16(f);
    return *reinterpret_cast<u16*>(&h);
}
__device__ __forceinline__ float ldin(int mode, const void* p, size_t i) {
    return mode ? ((const float*)p)[i] : b2f(((const u16*)p)[i]);
}
__device__ __forceinline__ float clamp30(float x) {
    return fminf(fmaxf(x, -30.0f), 30.0f);
}
__device__ __forceinline__ float sigmoidf_(float x) { return 1.0f / (1.0f + __expf(-x)); }
__device__ __forceinline__ float tanhf_(float x) {
    float e = __expf(2.0f * x);
    return 1.0f - 2.0f / (e + 1.0f);
}
__device__ __forceinline__ int dot4i8(u32 a, u32 b, int acc) {
#if __has_builtin(__builtin_amdgcn_sdot4)
    return __builtin_amdgcn_sdot4(a, b, acc, false);
#else
    acc += (int)(signed char)(a)       * (int)(signed char)(b);
    acc += (int)(signed char)(a >> 8)  * (int)(signed char)(b >> 8);
    acc += (int)(signed char)(a >> 16) * (int)(signed char)(b >> 16);
    acc += (int)(signed char)(a >> 24) * (int)(signed char)(b >> 24);
    return acc;
#endif
}

// ---------- K0: dtype sniffer (validated) ----------
__global__ void sniff_kernel(const u16* __restrict__ wemb) {
    int sane = 0;
    for (int i = 0; i < 2048; ++i) {
        int ex = (wemb[i] >> 7) & 0xFF;
        if (ex == 0 || (ex >= 96 && ex <= 143)) ++sane;
    }
    g_mode = (sane >= 1900) ? 0 : 1;
}

// ---------- K0b: Wih -> MFMA A-fragment order (r3-validated) ----------
__global__ __launch_bounds__(256) void prep_wa(const void* __restrict__ src) {
    const int mode = g_mode;
    int i = blockIdx.x * 256 + threadIdx.x;          // dst flat index, 0..131071
    int j = i & 7, l = (i >> 3) & 63, ks = (i >> 9) & 3, ct = i >> 11;
    int c = ct * 16 + (l & 15);
    int e = ks * 32 + (l >> 4) * 8 + j;
    int row = ((c & 3) << 8) + (c >> 2);
    g_WA[i] = f2b(ldin(mode, src, (size_t)row * E_ + e));
}

// ---------- K0c: Whh -> int8, unit-major quad layout [u][j][g]; + gate biases ----------
__global__ __launch_bounds__(256) void prep_wi8(const void* __restrict__ src,
                                                const void* __restrict__ bih,
                                                const void* __restrict__ bhh) {
    const int mode = g_mode;
    int c = blockIdx.x * 256 + threadIdx.x;          // c = 4u+g, 0..1023
    int row = ((c & 3) << 8) + (c >> 2);             // gate*256 + unit (validated)
    g_bias[c] = ldin(mode, bih, row) + ldin(mode, bhh, row);
    const size_t base = (size_t)row * H_;
    float m = 0.0f;
    for (int k = 0; k < H_; ++k) m = fmaxf(m, fabsf(ldin(mode, src, base + k)));
    float inv = (m > 0.0f) ? 127.0f / m : 0.0f;
    g_wscale[c] = m / (127.0f * 127.0f);             // w-scale * h-scale(1/127)
    for (int j = 0; j < 64; ++j) {
        u32 pk = 0;
#pragma unroll
        for (int i = 0; i < 4; ++i) {
            int q = (int)rintf(ldin(mode, src, base + 4 * j + i) * inv);
            q = max(-127, min(127, q));
            pk |= ((u32)(q & 0xff)) << (8 * i);
        }
        g_Wi8[(size_t)(c >> 2) * 256 + j * 4 + (c & 3)] = pk;
    }
}

// ---------- K0d: g_Wi8 -> MFMA i8 A-frag order (pure dword gather; r5-validated) ----------
__global__ __launch_bounds__(256) void prep_wqa() {
    int i = blockIdx.x * 256 + threadIdx.x;          // dword idx 0..65535
    int d = i & 1, r = i >> 1;
    int kt = r & 7, mt = (r >> 3) & 7, l = (r >> 6) & 63, w = r >> 12;
    int c = w * 128 + mt * 16 + (l & 15);
    int k0 = kt * 32 + ((l >> 4) << 3) + d * 4;
    g_WqA[i] = g_Wi8[(size_t)(c >> 2) * 256 + (k0 >> 2) * 4 + (c & 3)];
}

// ---------- K1: fused embedding (VALU) + input projection (MFMA, r3-validated) ----------
__global__ __launch_bounds__(256) void xg_mfma(const void* __restrict__ pw,
                                               const void* __restrict__ Wemb,
                                               const void* __restrict__ bemb) {
    const int mode = g_mode;
    const int t = threadIdx.x;
    const int m0 = blockIdx.x * 16;
    __shared__ float pw16[16][W_ + 2];
    __shared__ float Wl[E_ * 51];
    __shared__ __align__(16) u16 embL[16][136];

    for (int i = t; i < E_ * W_; i += 256) {
        int e = i / W_, w = i - e * W_;
        Wl[e * 51 + w] = ldin(mode, Wemb, i);
    }
    for (int i = t; i < 16 * W_; i += 256) {
        int r = i / W_, w = i - r * W_;
        pw16[r][w] = ldin(mode, pw, (size_t)(m0 + r) * W_ + w);
    }
    __syncthreads();

#pragma unroll
    for (int i = 0; i < 8; ++i) {
        int idx = i * 256 + t;
        int r = idx >> 7, e = idx & 127;
        float a = ldin(mode, bemb, e);
        const float* wr = &Wl[e * 51];
#pragma unroll
        for (int w = 0; w < W_; ++w) a = fmaf(pw16[r][w], wr[w], a);
        embL[r][e] = f2b(fmaxf(a, 0.0f));
    }
    __syncthreads();

    const int l = t & 63;
    const int wv = t >> 6;
    short8 Bf0 = *(const short8*)&embL[l & 15][0 * 32 + (l >> 4) * 8];
    short8 Bf1 = *(const short8*)&embL[l & 15][1 * 32 + (l >> 4) * 8];
    short8 Bf2 = *(const short8*)&embL[l & 15][2 * 32 + (l >> 4) * 8];
    short8 Bf3 = *(const short8*)&embL[l & 15][3 * 32 + (l >> 4) * 8];
    const short8* wa = (const short8*)g_WA;
    const int m = m0 + (l & 15);
#pragma unroll
    for (int tt = 0; tt < 16; ++tt) {
        const int ct = wv * 16 + tt;
        const int cbase = ct * 16;
        const float4 bv = *(const float4*)(g_bias + cbase + 4 * (l >> 4));
        f32x4 acc = {bv.x, bv.y, bv.z, bv.w};
        acc = __builtin_amdgcn_mfma_f32_16x16x32_bf16(wa[(ct * 4 + 0) * 64 + l], Bf0, acc, 0, 0, 0);
        acc = __builtin_amdgcn_mfma_f32_16x16x32_bf16(wa[(ct * 4 + 1) * 64 + l], Bf1, acc, 0, 0, 0);
        acc = __builtin_amdgcn_mfma_f32_16x16x32_bf16(wa[(ct * 4 + 2) * 64 + l], Bf2, acc, 0, 0, 0);
        acc = __builtin_amdgcn_mfma_f32_16x16x32_bf16(wa[(ct * 4 + 3) * 64 + l], Bf3, acc, 0, 0, 0);
        u32 p0 = (u32)f2b(acc[0]) | ((u32)f2b(acc[1]) << 16);
        u32 p1 = (u32)f2b(acc[2]) | ((u32)f2b(acc[3]) << 16);
        uint2 pv; pv.x = p0; pv.y = p1;
        *(uint2*)(g_xg + (size_t)m * G_ + cbase + 4 * (l >> 4)) = pv;
    }
}

// ---------- K2: HYBRID recurrence — dot4 waves + MFMA waves on separate pipes ----------
// 512 thr, 8 waves, 2 waves/EU. Waves 0-3 (one per SIMD): r3-validated split-2 dot4
// path for units 0..127 (~845cy VALU). Waves 4-7 (one per SIMD): r5-validated i8
// MFMA path for units 128..255 (64 MFMA/wave -> ~1024cy matrix pipe). The two pipes
// run concurrently per SIMD (m114), halving the per-step issue floor vs either alone.
// Both paths' weights load into the SAME 32 v4u regs (base chosen per wave; both
// index (w*64+l)*128). Integer math bit-identical to r3/r5 -> absmax unchanged.
#define MFMAI8(a, b, c) __builtin_amdgcn_mfma_i32_16x16x32_i8((a), (b), (c), 0, 0, 0)
#define MKQ(lo, hi) ((long)((((unsigned long long)(hi)) << 32) | (lo)))
#define MKL(v) ((long)((((unsigned long long)(v).y) << 32) | (v).x))

__global__ __launch_bounds__(512)
__attribute__((amdgpu_waves_per_eu(2, 2)))
void lstm_hybrid(const void* __restrict__ h0, const void* __restrict__ c0) {
    const int mode = g_mode;
    const int t = threadIdx.x;
    const int b = blockIdx.x;
    const int w = t >> 6;
    const int l = t & 63;
    const int half = t & 1;                 // dot-path k-half
    const bool isdot = (w < 4);
    const bool actv = isdot ? (half == 0) : (l < 32);
    const int u = isdot ? (t >> 1) : (w * 32 + (l & 31));   // unit this lane activates
    const int lg8 = (l >> 4) << 3;          // MFMA B-frag k-byte offset
    const int lg4 = (l >> 4) << 2;          // MFMA D row-quad offset
    const bool lq0 = ((l & 15) == 0);

    __shared__ __align__(16) u32 h8[2][64];   // double-buffered h (i8), 2x256 B
    __shared__ __align__(16) int gb[8][128];  // MFMA gate bounce (rows 4..7 used)

    // --- 32 quads into NAMED v4u regs; base per wave: dot->g_Wi8, mfma->g_WqA.
    // Both paths index (w*64+l)*128 = t*128 (dot: u*256+half*128; mfma: r5 rows w*128+..).
    v4u R00, R01, R02, R03, R04, R05, R06, R07, R08, R09, R10, R11, R12, R13, R14, R15;
    v4u R16, R17, R18, R19, R20, R21, R22, R23, R24, R25, R26, R27, R28, R29, R30, R31;
    {
        const u32* wp = (isdot ? g_Wi8 : g_WqA) + (size_t)t * 128;
        asm volatile(
            "global_load_dwordx4 %0, %16, off\n\t"
            "global_load_dwordx4 %1, %16, off offset:16\n\t"
            "global_load_dwordx4 %2, %16, off offset:32\n\t"
            "global_load_dwordx4 %3, %16, off offset:48\n\t"
            "global_load_dwordx4 %4, %16, off offset:64\n\t"
            "global_load_dwordx4 %5, %16, off offset:80\n\t"
            "global_load_dwordx4 %6, %16, off offset:96\n\t"
            "global_load_dwordx4 %7, %16, off offset:112\n\t"
            "global_load_dwordx4 %8, %16, off offset:128\n\t"
            "global_load_dwordx4 %9, %16, off offset:144\n\t"
            "global_load_dwordx4 %10, %16, off offset:160\n\t"
            "global_load_dwordx4 %11, %16, off offset:176\n\t"
            "global_load_dwordx4 %12, %16, off offset:192\n\t"
            "global_load_dwordx4 %13, %16, off offset:208\n\t"
            "global_load_dwordx4 %14, %16, off offset:224\n\t"
            "global_load_dwordx4 %15, %16, off offset:240\n\t"
            "s_waitcnt vmcnt(0)"
            : "=&v"(R00), "=&v"(R01), "=&v"(R02), "=&v"(R03),
              "=&v"(R04), "=&v"(R05), "=&v"(R06), "=&v"(R07),
              "=&v"(R08), "=&v"(R09), "=&v"(R10), "=&v"(R11),
              "=&v"(R12), "=&v"(R13), "=&v"(R14), "=&v"(R15)
            : "v"(wp));
        asm volatile(
            "global_load_dwordx4 %0, %16, off offset:256\n\t"
            "global_load_dwordx4 %1, %16, off offset:272\n\t"
            "global_load_dwordx4 %2, %16, off offset:288\n\t"
            "global_load_dwordx4 %3, %16, off offset:304\n\t"
            "global_load_dwordx4 %4, %16, off offset:320\n\t"
            "global_load_dwordx4 %5, %16, off offset:336\n\t"
            "global_load_dwordx4 %6, %16, off offset:352\n\t"
            "global_load_dwordx4 %7, %16, off offset:368\n\t"
            "global_load_dwordx4 %8, %16, off offset:384\n\t"
            "global_load_dwordx4 %9, %16, off offset:400\n\t"
            "global_load_dwordx4 %10, %16, off offset:416\n\t"
            "global_load_dwordx4 %11, %16, off offset:432\n\t"
            "global_load_dwordx4 %12, %16, off offset:448\n\t"
            "global_load_dwordx4 %13, %16, off offset:464\n\t"
            "global_load_dwordx4 %14, %16, off offset:480\n\t"
            "global_load_dwordx4 %15, %16, off offset:496\n\t"
            "s_waitcnt vmcnt(0)"
            : "=&v"(R16), "=&v"(R17), "=&v"(R18), "=&v"(R19),
              "=&v"(R20), "=&v"(R21), "=&v"(R22), "=&v"(R23),
              "=&v"(R24), "=&v"(R25), "=&v"(R26), "=&v"(R27),
              "=&v"(R28), "=&v"(R29), "=&v"(R30), "=&v"(R31)
            : "v"(wp));
    }

    const float4 wsc4 = *(const float4*)(g_wscale + 4 * u);   // hoisted dequant scales
    const u16* xp = g_xg + (size_t)b * S_ * G_ + 4 * u;
    float* hsp = g_hs + (size_t)b * S_ * H_ + u;
    float c_reg = 0.0f;
    ushort4 xqA, xqB;
    xqA.x = xqA.y = xqA.z = xqA.w = 0;
    xqB = xqA;

    if (t < H_ / 4) {                       // pack h0 into h8[0] (r3-validated init)
        u32 pk = 0;
#pragma unroll
        for (int i = 0; i < 4; ++i) {
            float h = ldin(mode, h0, (size_t)b * H_ + 4 * t + i);
            int q = (int)rintf(fminf(fmaxf(h, -1.0f), 1.0f) * 127.0f);
            pk |= ((u32)(q & 0xff)) << (8 * i);
        }
        h8[0][t] = pk;
    }
    if (actv) {
        c_reg = ldin(mode, c0, (size_t)b * H_ + u);
        xqA = *(const ushort4*)(xp);
        xqB = *(const ushort4*)(xp + G_);
    }
    asm volatile("s_waitcnt lgkmcnt(0)\n\t"
                 "s_barrier" ::: "memory");

#define DOTG(HV, RA, RB, RC, RD)                                              \
            ai = dot4i8(HV.x, RA.x, ai); af = dot4i8(HV.x, RA.y, af);         \
            ag = dot4i8(HV.x, RA.z, ag); ao = dot4i8(HV.x, RA.w, ao);         \
            ai = dot4i8(HV.y, RB.x, ai); af = dot4i8(HV.y, RB.y, af);         \
            ag = dot4i8(HV.y, RB.z, ag); ao = dot4i8(HV.y, RB.w, ao);         \
            ai = dot4i8(HV.z, RC.x, ai); af = dot4i8(HV.z, RC.y, af);         \
            ag = dot4i8(HV.z, RC.z, ag); ao = dot4i8(HV.z, RC.w, ao);         \
            ai = dot4i8(HV.w, RD.x, ai); af = dot4i8(HV.w, RD.y, af);         \
            ag = dot4i8(HV.w, RD.z, ag); ao = dot4i8(HV.w, RD.w, ao);

#define MTROW(mt, RA, RB, RC, RD, B0, B1, B2, B3, B4, B5, B6, B7)             \
    {                                                                         \
        i32x4 acc = {0, 0, 0, 0};                                             \
        acc = MFMAI8(MKQ(RA.x, RA.y), B0, acc);                               \
        acc = MFMAI8(MKQ(RA.z, RA.w), B1, acc);                               \
        acc = MFMAI8(MKQ(RB.x, RB.y), B2, acc);                               \
        acc = MFMAI8(MKQ(RB.z, RB.w), B3, acc);                               \
        acc = MFMAI8(MKQ(RC.x, RC.y), B4, acc);                               \
        acc = MFMAI8(MKQ(RC.z, RC.w), B5, acc);                               \
        acc = MFMAI8(MKQ(RD.x, RD.y), B6, acc);                               \
        acc = MFMAI8(MKQ(RD.z, RD.w), B7, acc);                               \
        if (lq0) *(i32x4*)&gb[w][(mt) * 16 + lg4] = acc;                      \
    }

#define ACT(GI, GF, GG, GO, S, XQ, SN)                                        \
    {                                                                         \
        const ushort4 xv = XQ;                                                \
        XQ = *(const ushort4*)(xp + (size_t)(SN) * G_);                       \
        float gi = (GI) * wsc4.x + b2f(xv.x);                                 \
        float gf = (GF) * wsc4.y + b2f(xv.y);                                 \
        float gg = (GG) * wsc4.z + b2f(xv.z);                                 \
        float go = (GO) * wsc4.w + b2f(xv.w);                                 \
        float ii = sigmoidf_(gi);                                             \
        float ff = sigmoidf_(gf);                                             \
        float gt = tanhf_(gg);                                                \
        float oo = sigmoidf_(go);                                             \
        c_reg = fmaf(ff, c_reg, ii * gt);                                     \
        float hv = oo * tanhf_(c_reg);                                        \
        ((u8*)&h8[((S) + 1) & 1][0])[u] =                                     \
            (u8)((int)rintf(fminf(fmaxf(hv, -1.0f), 1.0f) * 127.0f) & 0xff);  \
        hsp[(size_t)(S) * H_] = hv;                                           \
    }

#define STEP(S, XQ, SN)                                                       \
    if (isdot) {                                                              \
        const uint4* hp = (const uint4*)h8[(S) & 1] + half * 8;               \
        uint4 h0v = hp[0], h1v = hp[1], h2v = hp[2], h3v = hp[3];             \
        uint4 h4v = hp[4], h5v = hp[5], h6v = hp[6], h7v = hp[7];             \
        int ai = 0, af = 0, ag = 0, ao = 0;                                   \
        DOTG(h0v, R00, R01, R02, R03)                                         \
        DOTG(h1v, R04, R05, R06, R07)                                         \
        DOTG(h2v, R08, R09, R10, R11)                                         \
        DOTG(h3v, R12, R13, R14, R15)                                         \
        DOTG(h4v, R16, R17, R18, R19)                                         \
        DOTG(h5v, R20, R21, R22, R23)                                         \
        DOTG(h6v, R24, R25, R26, R27)                                         \
        DOTG(h7v, R28, R29, R30, R31)                                         \
        ai += __shfl_xor(ai, 1, 64);                                          \
        af += __shfl_xor(af, 1, 64);                                          \
        ag += __shfl_xor(ag, 1, 64);                                          \
        ao += __shfl_xor(ao, 1, 64);                                          \
        if (half == 0) ACT((float)ai, (float)af, (float)ag, (float)ao, S, XQ, SN) \
    } else {                                                                  \
        const u8* hb = (const u8*)&h8[(S) & 1][0];                            \
        uint2 bf0 = *(const uint2*)(hb + 0 * 32 + lg8);                       \
        uint2 bf1 = *(const uint2*)(hb + 1 * 32 + lg8);                       \
        uint2 bf2 = *(const uint2*)(hb + 2 * 32 + lg8);                       \
        uint2 bf3 = *(const uint2*)(hb + 3 * 32 + lg8);                       \
        uint2 bf4 = *(const uint2*)(hb + 4 * 32 + lg8);                       \
        uint2 bf5 = *(const uint2*)(hb + 5 * 32 + lg8);                       \
        uint2 bf6 = *(const uint2*)(hb + 6 * 32 + lg8);                       \
        uint2 bf7 = *(const uint2*)(hb + 7 * 32 + lg8);                       \
        const long Bl0 = MKL(bf0), Bl1 = MKL(bf1), Bl2 = MKL(bf2);            \
        const long Bl3 = MKL(bf3), Bl4 = MKL(bf4), Bl5 = MKL(bf5);            \
        const long Bl6 = MKL(bf6), Bl7 = MKL(bf7);                            \
        MTROW(0, R00, R01, R02, R03, Bl0, Bl1, Bl2, Bl3, Bl4, Bl5, Bl6, Bl7)  \
        MTROW(1, R04, R05, R06, R07, Bl0, Bl1, Bl2, Bl3, Bl4, Bl5, Bl6, Bl7)  \
        MTROW(2, R08, R09, R10, R11, Bl0, Bl1, Bl2, Bl3, Bl4, Bl5, Bl6, Bl7)  \
        MTROW(3, R12, R13, R14, R15, Bl0, Bl1, Bl2, Bl3, Bl4, Bl5, Bl6, Bl7)  \
        MTROW(4, R16, R17, R18, R19, Bl0, Bl1, Bl2, Bl3, Bl4, Bl5, Bl6, Bl7)  \
        MTROW(5, R20, R21, R22, R23, Bl0, Bl1, Bl2, Bl3, Bl4, Bl5, Bl6, Bl7)  \
        MTROW(6, R24, R25, R26, R27, Bl0, Bl1, Bl2, Bl3, Bl4, Bl5, Bl6, Bl7)  \
        MTROW(7, R28, R29, R30, R31, Bl0, Bl1, Bl2, Bl3, Bl4, Bl5, Bl6, Bl7)  \
        asm volatile("s_waitcnt lgkmcnt(0)" ::: "memory");                    \
        if (l < 32) {                                                         \
            const i32x4 gv = *(const i32x4*)&gb[w][4 * (l & 31)];             \
            ACT((float)gv.x, (float)gv.y, (float)gv.z, (float)gv.w, S, XQ, SN) \
        }                                                                     \
    }                                                                         \
    asm volatile("s_waitcnt lgkmcnt(0)\n\t"                                   \
                 "s_barrier" ::: "memory");

    for (int s0 = 0; s0 < S_; s0 += 2) {
        STEP(s0,     xqA, (s0 + 2 < S_) ? s0 + 2 : s0)
        STEP(s0 + 1, xqB, (s0 + 3 < S_) ? s0 + 3 : s0 + 1)
    }
#undef STEP
#undef ACT
#undef MTROW
#undef DOTG
}

// ---------- K3: output head — one wave per (s,b), fp32 h ----------
__global__ __launch_bounds__(256) void head_kernel(const void* __restrict__ Wout,
                                                   const void* __restrict__ bout,
                                                   void* __restrict__ yv) {
    const int mode = g_mode;
    const int t = threadIdx.x;
    const int idx = blockIdx.x * 4 + (t >> 6);   // (s,b) pair
    const int l = t & 63;
    const int s = idx >> 6, b = idx & 63;
    const float* hb = g_hs + ((size_t)b * S_ + s) * H_ + 4 * l;
    float4 hv = *(const float4*)hb;
    float p = hv.x * ldin(mode, Wout, 4 * l + 0)
            + hv.y * ldin(mode, Wout, 4 * l + 1)
            + hv.z * ldin(mode, Wout, 4 * l + 2)
            + hv.w * ldin(mode, Wout, 4 * l + 3);
#pragma unroll
    for (int off = 32; off > 0; off >>= 1) p += __shfl_down(p, off, 64);
    if (l == 0) {
        float yf = sigmoidf_(clamp30(p + ldin(mode, bout, 0)));
        if (mode) ((float*)yv)[(size_t)s * B_ + b] = yf;
        else      ((u16*)yv)[(size_t)s * B_ + b] = f2b(yf);
    }
}

extern "C" void kernel_launch(void* const* d_in, const int* in_sizes, int n_in,
                              void* d_out, int out_size, void* d_ws, size_t ws_size,
                              hipStream_t stream) {
    const void* pw   = d_in[0];   // [B,S,50]
    const void* Wemb = d_in[1];   // [E,50]
    const void* bemb = d_in[2];   // [E]
    const void* Wih  = d_in[3];   // [G,E]
    const void* Whh  = d_in[4];   // [G,H]
    const void* bih  = d_in[5];   // [G]
    const void* bhh  = d_in[6];   // [G]
    const void* Wout = d_in[7];   // [1,H]
    const void* bout = d_in[8];   // [1]
    const void* h0   = d_in[9];   // [B,H]
    const void* c0   = d_in[10];  // [B,H]
    void* y = d_out;              // [S,B]
    (void)d_ws; (void)ws_size;

    sniff_kernel<<<1, 1, 0, stream>>>((const u16*)Wemb);
    prep_wa<<<(E_ * G_) / 256, 256, 0, stream>>>(Wih);
    prep_wi8<<<G_ / 256, 256, 0, stream>>>(Whh, bih, bhh);
    prep_wqa<<<(G_ * 64) / 256, 256, 0, stream>>>();
    xg_mfma<<<(B_ * S_) / 16, 256, 0, stream>>>(pw, Wemb, bemb);
    lstm_hybrid<<<B_, 512, 0, stream>>>(h0, c0);
    head_kernel<<<(S_ * B_) / 4, 256, 0, stream>>>(Wout, bout, y);
}

// Round 8
// 2565.859 us; speedup vs baseline: 1.5510x; 1.3981x over previous
//
#include <hip/hip_runtime.h>
#include <hip/hip_bf16.h>

// B=64, S=2048, WIN=50, E=128, H=256, G=4H=1024.
#define B_ 64
#define S_ 2048
#define W_ 50
#define E_ 128
#define H_ 256
#define G_ 1024

typedef unsigned short u16;
typedef unsigned int u32;
typedef unsigned char u8;
typedef unsigned int v4u __attribute__((ext_vector_type(4)));
typedef __attribute__((ext_vector_type(8))) short short8;   // bf16x8 MFMA frag
typedef __attribute__((ext_vector_type(4))) float f32x4;    // MFMA acc

// Module-global scratch (BSS; d_ws untrusted).
__device__ int g_mode;                          // 0 = bf16 buffers, 1 = fp32 buffers
__device__ u16 g_WA[E_ * G_];                   // Wih in MFMA A-frag order (bf16) [r3-validated]
__device__ float g_bias[G_];                    // bih+bhh, gate-interleaved c = 4u+q
__device__ u32 g_Wi8[G_ * 64];                  // [u][j][g]: pack4(Whh col c=4u+g, k=4j..4j+3)
__device__ float g_wscale[G_];                  // per-column dequant: max|W[:,c]| /(127*127), c=4u+g
__device__ u16 g_xg[(size_t)B_ * S_ * G_];      // [b][s][1024] bf16, biases folded (validated)
__device__ float g_hs[(size_t)B_ * S_ * H_];    // [b][s][u] fp32 hidden states (for output head)

__device__ __forceinline__ float b2f(u16 u) {
    union { u32 i; float f; } v;
    v.i = ((u32)u) << 16;
    return v.f;
}
__device__ __forceinline__ u16 f2b(float f) {
    __hip_bfloat16 h = __float2bfloat16(f);
    return *reinterpret_cast<u16*>(&h);
}
__device__ __forceinline__ float ldin(int mode, const void* p, size_t i) {
    return mode ? ((const float*)p)[i] : b2f(((const u16*)p)[i]);
}
__device__ __forceinline__ float clamp30(float x) {
    return fminf(fmaxf(x, -30.0f), 30.0f);
}
__device__ __forceinline__ float sigmoidf_(float x) { return 1.0f / (1.0f + __expf(-x)); }
__device__ __forceinline__ float tanhf_(float x) {
    float e = __expf(2.0f * x);
    return 1.0f - 2.0f / (e + 1.0f);
}
__device__ __forceinline__ int dot4i8(u32 a, u32 b, int acc) {
#if __has_builtin(__builtin_amdgcn_sdot4)
    return __builtin_amdgcn_sdot4(a, b, acc, false);
#else
    acc += (int)(signed char)(a)       * (int)(signed char)(b);
    acc += (int)(signed char)(a >> 8)  * (int)(signed char)(b >> 8);
    acc += (int)(signed char)(a >> 16) * (int)(signed char)(b >> 16);
    acc += (int)(signed char)(a >> 24) * (int)(signed char)(b >> 24);
    return acc;
#endif
}

// ---------- K0: dtype sniffer (validated) ----------
__global__ void sniff_kernel(const u16* __restrict__ wemb) {
    int sane = 0;
    for (int i = 0; i < 2048; ++i) {
        int ex = (wemb[i] >> 7) & 0xFF;
        if (ex == 0 || (ex >= 96 && ex <= 143)) ++sane;
    }
    g_mode = (sane >= 1900) ? 0 : 1;
}

// ---------- K0b: Wih -> MFMA A-fragment order (r3-validated) ----------
__global__ __launch_bounds__(256) void prep_wa(const void* __restrict__ src) {
    const int mode = g_mode;
    int i = blockIdx.x * 256 + threadIdx.x;          // dst flat index, 0..131071
    int j = i & 7, l = (i >> 3) & 63, ks = (i >> 9) & 3, ct = i >> 11;
    int c = ct * 16 + (l & 15);
    int e = ks * 32 + (l >> 4) * 8 + j;
    int row = ((c & 3) << 8) + (c >> 2);
    g_WA[i] = f2b(ldin(mode, src, (size_t)row * E_ + e));
}

// ---------- K0c: Whh -> int8, unit-major quad layout [u][j][g]; + gate biases ----------
__global__ __launch_bounds__(256) void prep_wi8(const void* __restrict__ src,
                                                const void* __restrict__ bih,
                                                const void* __restrict__ bhh) {
    const int mode = g_mode;
    int c = blockIdx.x * 256 + threadIdx.x;          // c = 4u+g, 0..1023
    int row = ((c & 3) << 8) + (c >> 2);             // gate*256 + unit (validated)
    g_bias[c] = ldin(mode, bih, row) + ldin(mode, bhh, row);
    const size_t base = (size_t)row * H_;
    float m = 0.0f;
    for (int k = 0; k < H_; ++k) m = fmaxf(m, fabsf(ldin(mode, src, base + k)));
    float inv = (m > 0.0f) ? 127.0f / m : 0.0f;
    g_wscale[c] = m / (127.0f * 127.0f);             // w-scale * h-scale(1/127)
    for (int j = 0; j < 64; ++j) {
        u32 pk = 0;
#pragma unroll
        for (int i = 0; i < 4; ++i) {
            int q = (int)rintf(ldin(mode, src, base + 4 * j + i) * inv);
            q = max(-127, min(127, q));
            pk |= ((u32)(q & 0xff)) << (8 * i);
        }
        g_Wi8[(size_t)(c >> 2) * 256 + j * 4 + (c & 3)] = pk;
    }
}

// ---------- K1: fused embedding (VALU) + input projection (MFMA, r3-validated) ----------
// r7 change (isolated): e = (i*256+t)&127 == t&127 is CONSTANT across the 8 row
// iterations, so the 50-float W-row is cached in registers once (50 ds_reads
// instead of 400/thread). Summation order unchanged -> bitwise-identical output.
__global__ __launch_bounds__(256) void xg_mfma(const void* __restrict__ pw,
                                               const void* __restrict__ Wemb,
                                               const void* __restrict__ bemb) {
    const int mode = g_mode;
    const int t = threadIdx.x;
    const int m0 = blockIdx.x * 16;
    __shared__ float pw16[16][W_ + 2];
    __shared__ float Wl[E_ * 51];
    __shared__ __align__(16) u16 embL[16][136];

    for (int i = t; i < E_ * W_; i += 256) {
        int e = i / W_, w = i - e * W_;
        Wl[e * 51 + w] = ldin(mode, Wemb, i);
    }
    for (int i = t; i < 16 * W_; i += 256) {
        int r = i / W_, w = i - r * W_;
        pw16[r][w] = ldin(mode, pw, (size_t)(m0 + r) * W_ + w);
    }
    __syncthreads();

    {
        const int e = t & 127;
        float wreg[W_];
#pragma unroll
        for (int w = 0; w < W_; ++w) wreg[w] = Wl[e * 51 + w];
        const float bb = ldin(mode, bemb, e);
#pragma unroll
        for (int i = 0; i < 8; ++i) {
            const int r = i * 2 + (t >> 7);          // same (r,e) coverage as r3
            float a = bb;
#pragma unroll
            for (int w = 0; w < W_; ++w) a = fmaf(pw16[r][w], wreg[w], a);
            embL[r][e] = f2b(fmaxf(a, 0.0f));
        }
    }
    __syncthreads();

    const int l = t & 63;
    const int wv = t >> 6;
    short8 Bf0 = *(const short8*)&embL[l & 15][0 * 32 + (l >> 4) * 8];
    short8 Bf1 = *(const short8*)&embL[l & 15][1 * 32 + (l >> 4) * 8];
    short8 Bf2 = *(const short8*)&embL[l & 15][2 * 32 + (l >> 4) * 8];
    short8 Bf3 = *(const short8*)&embL[l & 15][3 * 32 + (l >> 4) * 8];
    const short8* wa = (const short8*)g_WA;
    const int m = m0 + (l & 15);
#pragma unroll
    for (int tt = 0; tt < 16; ++tt) {
        const int ct = wv * 16 + tt;
        const int cbase = ct * 16;
        const float4 bv = *(const float4*)(g_bias + cbase + 4 * (l >> 4));
        f32x4 acc = {bv.x, bv.y, bv.z, bv.w};
        acc = __builtin_amdgcn_mfma_f32_16x16x32_bf16(wa[(ct * 4 + 0) * 64 + l], Bf0, acc, 0, 0, 0);
        acc = __builtin_amdgcn_mfma_f32_16x16x32_bf16(wa[(ct * 4 + 1) * 64 + l], Bf1, acc, 0, 0, 0);
        acc = __builtin_amdgcn_mfma_f32_16x16x32_bf16(wa[(ct * 4 + 2) * 64 + l], Bf2, acc, 0, 0, 0);
        acc = __builtin_amdgcn_mfma_f32_16x16x32_bf16(wa[(ct * 4 + 3) * 64 + l], Bf3, acc, 0, 0, 0);
        u32 p0 = (u32)f2b(acc[0]) | ((u32)f2b(acc[1]) << 16);
        u32 p1 = (u32)f2b(acc[2]) | ((u32)f2b(acc[3]) << 16);
        uint2 pv; pv.x = p0; pv.y = p1;
        *(uint2*)(g_xg + (size_t)m * G_ + cbase + 4 * (l >> 4)) = pv;
    }
}

// ---------- K2: recurrence, split-K pairs (512 thr, 8 waves, 2 waves/EU) ----------
// r3-VALIDATED VERBATIM (2087us): 4-step unrolled body (~6.5KB, fits L1I), rolling
// single-buffer xq prefetch (distance 4), raw lgkmcnt-only barriers, ds_write_b8
// publish, fire-and-forget h store.
__global__ __launch_bounds__(512)
__attribute__((amdgpu_waves_per_eu(2, 2)))
void lstm_split(const void* __restrict__ h0, const void* __restrict__ c0) {
    const int mode = g_mode;
    const int t = threadIdx.x;
    const int b = blockIdx.x;
    const int u = t >> 1;
    const int half = t & 1;

    __shared__ __align__(16) u32 h8[2][H_ / 4];  // double-buffered h (i8), 2x256 B

    // --- 32 weight quads into named v4u via asm (validated pattern, waitcnt per block) ---
    v4u W00, W01, W02, W03, W04, W05, W06, W07, W08, W09, W10, W11, W12, W13, W14, W15;
    v4u W16, W17, W18, W19, W20, W21, W22, W23, W24, W25, W26, W27, W28, W29, W30, W31;
    {
        const u32* wp = g_Wi8 + (size_t)t * 128;   // = u*256 + half*128
        asm volatile(
            "global_load_dwordx4 %0, %16, off\n\t"
            "global_load_dwordx4 %1, %16, off offset:16\n\t"
            "global_load_dwordx4 %2, %16, off offset:32\n\t"
            "global_load_dwordx4 %3, %16, off offset:48\n\t"
            "global_load_dwordx4 %4, %16, off offset:64\n\t"
            "global_load_dwordx4 %5, %16, off offset:80\n\t"
            "global_load_dwordx4 %6, %16, off offset:96\n\t"
            "global_load_dwordx4 %7, %16, off offset:112\n\t"
            "global_load_dwordx4 %8, %16, off offset:128\n\t"
            "global_load_dwordx4 %9, %16, off offset:144\n\t"
            "global_load_dwordx4 %10, %16, off offset:160\n\t"
            "global_load_dwordx4 %11, %16, off offset:176\n\t"
            "global_load_dwordx4 %12, %16, off offset:192\n\t"
            "global_load_dwordx4 %13, %16, off offset:208\n\t"
            "global_load_dwordx4 %14, %16, off offset:224\n\t"
            "global_load_dwordx4 %15, %16, off offset:240\n\t"
            "s_waitcnt vmcnt(0)"
            : "=&v"(W00), "=&v"(W01), "=&v"(W02), "=&v"(W03),
              "=&v"(W04), "=&v"(W05), "=&v"(W06), "=&v"(W07),
              "=&v"(W08), "=&v"(W09), "=&v"(W10), "=&v"(W11),
              "=&v"(W12), "=&v"(W13), "=&v"(W14), "=&v"(W15)
            : "v"(wp));
        asm volatile(
            "global_load_dwordx4 %0, %16, off offset:256\n\t"
            "global_load_dwordx4 %1, %16, off offset:272\n\t"
            "global_load_dwordx4 %2, %16, off offset:288\n\t"
            "global_load_dwordx4 %3, %16, off offset:304\n\t"
            "global_load_dwordx4 %4, %16, off offset:320\n\t"
            "global_load_dwordx4 %5, %16, off offset:336\n\t"
            "global_load_dwordx4 %6, %16, off offset:352\n\t"
            "global_load_dwordx4 %7, %16, off offset:368\n\t"
            "global_load_dwordx4 %8, %16, off offset:384\n\t"
            "global_load_dwordx4 %9, %16, off offset:400\n\t"
            "global_load_dwordx4 %10, %16, off offset:416\n\t"
            "global_load_dwordx4 %11, %16, off offset:432\n\t"
            "global_load_dwordx4 %12, %16, off offset:448\n\t"
            "global_load_dwordx4 %13, %16, off offset:464\n\t"
            "global_load_dwordx4 %14, %16, off offset:480\n\t"
            "global_load_dwordx4 %15, %16, off offset:496\n\t"
            "s_waitcnt vmcnt(0)"
            : "=&v"(W16), "=&v"(W17), "=&v"(W18), "=&v"(W19),
              "=&v"(W20), "=&v"(W21), "=&v"(W22), "=&v"(W23),
              "=&v"(W24), "=&v"(W25), "=&v"(W26), "=&v"(W27),
              "=&v"(W28), "=&v"(W29), "=&v"(W30), "=&v"(W31)
            : "v"(wp));
    }

    const float4 wsc4 = *(const float4*)(g_wscale + 4 * u);
    float c_reg = (half == 0) ? ldin(mode, c0, (size_t)b * H_ + u) : 0.0f;

    if (t < H_ / 4) {
        u32 pk = 0;
#pragma unroll
        for (int i = 0; i < 4; ++i) {
            float h = ldin(mode, h0, (size_t)b * H_ + 4 * t + i);
            int q = (int)rintf(fminf(fmaxf(h, -1.0f), 1.0f) * 127.0f);
            pk |= ((u32)(q & 0xff)) << (8 * i);
        }
        h8[0][t] = pk;
    }
    const u16* xp = g_xg + (size_t)b * S_ * G_ + 4 * u;
    float* hsp = g_hs + (size_t)b * S_ * H_ + u;

    // prime rolling prefetch buffer (all lanes load; odd lanes' copies unused but
    // same cache lines -> no extra traffic, no divergence)
    ushort4 xq[4];
#pragma unroll
    for (int e = 0; e < 4; ++e)
        xq[e] = *(const ushort4*)(xp + (size_t)e * G_);

    asm volatile("s_waitcnt lgkmcnt(0)\n\t"
                 "s_barrier" ::: "memory");

#define DOTG(HV, WA, WB, WC, WD)                                              \
            ai = dot4i8(HV.x, WA.x, ai); af = dot4i8(HV.x, WA.y, af);         \
            ag = dot4i8(HV.x, WA.z, ag); ao = dot4i8(HV.x, WA.w, ao);         \
            ai = dot4i8(HV.y, WB.x, ai); af = dot4i8(HV.y, WB.y, af);         \
            ag = dot4i8(HV.y, WB.z, ag); ao = dot4i8(HV.y, WB.w, ao);         \
            ai = dot4i8(HV.z, WC.x, ai); af = dot4i8(HV.z, WC.y, af);         \
            ag = dot4i8(HV.z, WC.z, ag); ao = dot4i8(HV.z, WC.w, ao);         \
            ai = dot4i8(HV.w, WD.x, ai); af = dot4i8(HV.w, WD.y, af);         \
            ag = dot4i8(HV.w, WD.z, ag); ao = dot4i8(HV.w, WD.w, ao);

    for (int s0 = 0; s0 < S_; s0 += 4) {
#pragma unroll
        for (int e = 0; e < 4; ++e) {
            const int s = s0 + e;
            // consume current xq, immediately re-issue for s+4 (rolling prefetch)
            const ushort4 xv = xq[e];
            const int sn = (s + 4 < S_) ? s + 4 : s;
            xq[e] = *(const ushort4*)(xp + (size_t)sn * G_);

            const uint4* hp = (const uint4*)h8[s & 1] + half * 8;
            uint4 h0v = hp[0], h1v = hp[1], h2v = hp[2], h3v = hp[3];
            uint4 h4v = hp[4], h5v = hp[5], h6v = hp[6], h7v = hp[7];

            int ai = 0, af = 0, ag = 0, ao = 0;
            DOTG(h0v, W00, W01, W02, W03)
            DOTG(h1v, W04, W05, W06, W07)
            DOTG(h2v, W08, W09, W10, W11)
            DOTG(h3v, W12, W13, W14, W15)
            DOTG(h4v, W16, W17, W18, W19)
            DOTG(h5v, W20, W21, W22, W23)
            DOTG(h6v, W24, W25, W26, W27)
            DOTG(h7v, W28, W29, W30, W31)

            ai += __shfl_xor(ai, 1, 64);
            af += __shfl_xor(af, 1, 64);
            ag += __shfl_xor(ag, 1, 64);
            ao += __shfl_xor(ao, 1, 64);

            if (half == 0) {
                float gi = (float)ai * wsc4.x + b2f(xv.x);
                float gf = (float)af * wsc4.y + b2f(xv.y);
                float gg = (float)ag * wsc4.z + b2f(xv.z);
                float go = (float)ao * wsc4.w + b2f(xv.w);
                float ii = sigmoidf_(clamp30(gi));
                float ff = sigmoidf_(clamp30(gf));
                float gv = tanhf_(clamp30(gg));
                float oo = sigmoidf_(clamp30(go));
                c_reg = fmaf(ff, c_reg, ii * gv);
                float h = oo * tanhf_(c_reg);
                int q = (int)rintf(fminf(fmaxf(h, -1.0f), 1.0f) * 127.0f) & 0xff;
                ((u8*)h8[(s + 1) & 1])[u] = (u8)q;   // single-byte publish
                hsp[(size_t)s * H_] = h;             // fire-and-forget
            }
            // LDS ordering only; global loads/stores stay in flight
            asm volatile("s_waitcnt lgkmcnt(0)\n\t"
                         "s_barrier" ::: "memory");
        }
    }
#undef DOTG
}

// ---------- K3: output head — one wave per (s,b), fp32 h ----------
__global__ __launch_bounds__(256) void head_kernel(const void* __restrict__ Wout,
                                                   const void* __restrict__ bout,
                                                   void* __restrict__ yv) {
    const int mode = g_mode;
    const int t = threadIdx.x;
    const int idx = blockIdx.x * 4 + (t >> 6);   // (s,b) pair
    const int l = t & 63;
    const int s = idx >> 6, b = idx & 63;
    const float* hb = g_hs + ((size_t)b * S_ + s) * H_ + 4 * l;
    float4 hv = *(const float4*)hb;
    float p = hv.x * ldin(mode, Wout, 4 * l + 0)
            + hv.y * ldin(mode, Wout, 4 * l + 1)
            + hv.z * ldin(mode, Wout, 4 * l + 2)
            + hv.w * ldin(mode, Wout, 4 * l + 3);
#pragma unroll
    for (int off = 32; off > 0; off >>= 1) p += __shfl_down(p, off, 64);
    if (l == 0) {
        float yf = sigmoidf_(clamp30(p + ldin(mode, bout, 0)));
        if (mode) ((float*)yv)[(size_t)s * B_ + b] = yf;
        else      ((u16*)yv)[(size_t)s * B_ + b] = f2b(yf);
    }
}

extern "C" void kernel_launch(void* const* d_in, const int* in_sizes, int n_in,
                              void* d_out, int out_size, void* d_ws, size_t ws_size,
                              hipStream_t stream) {
    const void* pw   = d_in[0];   // [B,S,50]
    const void* Wemb = d_in[1];   // [E,50]
    const void* bemb = d_in[2];   // [E]
    const void* Wih  = d_in[3];   // [G,E]
    const void* Whh  = d_in[4];   // [G,H]
    const void* bih  = d_in[5];   // [G]
    const void* bhh  = d_in[6];   // [G]
    const void* Wout = d_in[7];   // [1,H]
    const void* bout = d_in[8];   // [1]
    const void* h0   = d_in[9];   // [B,H]
    const void* c0   = d_in[10];  // [B,H]
    void* y = d_out;              // [S,B]
    (void)d_ws; (void)ws_size;

    sniff_kernel<<<1, 1, 0, stream>>>((const u16*)Wemb);
    prep_wa<<<(E_ * G_) / 256, 256, 0, stream>>>(Wih);
    prep_wi8<<<G_ / 256, 256, 0, stream>>>(Whh, bih, bhh);
    xg_mfma<<<(B_ * S_) / 16, 256, 0, stream>>>(pw, Wemb, bemb);
    lstm_split<<<B_, 512, 0, stream>>>(h0, c0);
    head_kernel<<<(S_ * B_) / 4, 256, 0, stream>>>(Wout, bout, y);
}

// Round 9
// 2479.179 us; speedup vs baseline: 1.6052x; 1.0350x over previous
//
#include <hip/hip_runtime.h>
#include <hip/hip_bf16.h>

// B=64, S=2048, WIN=50, E=128, H=256, G=4H=1024.
#define B_ 64
#define S_ 2048
#define W_ 50
#define E_ 128
#define H_ 256
#define G_ 1024

typedef unsigned short u16;
typedef unsigned int u32;
typedef unsigned char u8;
typedef unsigned int v4u __attribute__((ext_vector_type(4)));
typedef __attribute__((ext_vector_type(8))) short short8;   // bf16x8 MFMA frag
typedef __attribute__((ext_vector_type(4))) float f32x4;    // MFMA acc

// Module-global scratch (BSS; d_ws untrusted).
__device__ int g_mode;                          // 0 = bf16 buffers, 1 = fp32 buffers
__device__ u16 g_WA[E_ * G_];                   // Wih in MFMA A-frag order (bf16) [r3-validated]
__device__ float g_bias[G_];                    // bih+bhh, gate-interleaved c = 4u+q
__device__ u32 g_Wi8[G_ * 64];                  // [u][j][g]: pack4(Whh col c=4u+g, k=4j..4j+3)
__device__ float g_wscale[G_];                  // per-column dequant: max|W[:,c]| /(127*127), c=4u+g
__device__ u16 g_xg[(size_t)B_ * S_ * G_];      // [b][s][1024] bf16, biases folded (validated)
__device__ float g_hs[(size_t)B_ * S_ * H_];    // [b][s][u] fp32 hidden states (for output head)

__device__ __forceinline__ float b2f(u16 u) {
    union { u32 i; float f; } v;
    v.i = ((u32)u) << 16;
    return v.f;
}
__device__ __forceinline__ u16 f2b(float f) {
    __hip_bfloat16 h = __float2bfloat16(f);
    return *reinterpret_cast<u16*>(&h);
}
__device__ __forceinline__ float ldin(int mode, const void* p, size_t i) {
    return mode ? ((const float*)p)[i] : b2f(((const u16*)p)[i]);
}
__device__ __forceinline__ float clamp30(float x) {
    return fminf(fmaxf(x, -30.0f), 30.0f);
}
__device__ __forceinline__ float sigmoidf_(float x) { return 1.0f / (1.0f + __expf(-x)); }
__device__ __forceinline__ float tanhf_(float x) {
    float e = __expf(2.0f * x);
    return 1.0f - 2.0f / (e + 1.0f);
}
__device__ __forceinline__ int dot4i8(u32 a, u32 b, int acc) {
#if __has_builtin(__builtin_amdgcn_sdot4)
    return __builtin_amdgcn_sdot4(a, b, acc, false);
#else
    acc += (int)(signed char)(a)       * (int)(signed char)(b);
    acc += (int)(signed char)(a >> 8)  * (int)(signed char)(b >> 8);
    acc += (int)(signed char)(a >> 16) * (int)(signed char)(b >> 16);
    acc += (int)(signed char)(a >> 24) * (int)(signed char)(b >> 24);
    return acc;
#endif
}

// ---------- K0: dtype sniffer (validated) ----------
__global__ void sniff_kernel(const u16* __restrict__ wemb) {
    int sane = 0;
    for (int i = 0; i < 2048; ++i) {
        int ex = (wemb[i] >> 7) & 0xFF;
        if (ex == 0 || (ex >= 96 && ex <= 143)) ++sane;
    }
    g_mode = (sane >= 1900) ? 0 : 1;
}

// ---------- K0b: Wih -> MFMA A-fragment order (r3-validated) ----------
__global__ __launch_bounds__(256) void prep_wa(const void* __restrict__ src) {
    const int mode = g_mode;
    int i = blockIdx.x * 256 + threadIdx.x;          // dst flat index, 0..131071
    int j = i & 7, l = (i >> 3) & 63, ks = (i >> 9) & 3, ct = i >> 11;
    int c = ct * 16 + (l & 15);
    int e = ks * 32 + (l >> 4) * 8 + j;
    int row = ((c & 3) << 8) + (c >> 2);
    g_WA[i] = f2b(ldin(mode, src, (size_t)row * E_ + e));
}

// ---------- K0c: Whh -> int8, unit-major quad layout [u][j][g]; + gate biases ----------
__global__ __launch_bounds__(256) void prep_wi8(const void* __restrict__ src,
                                                const void* __restrict__ bih,
                                                const void* __restrict__ bhh) {
    const int mode = g_mode;
    int c = blockIdx.x * 256 + threadIdx.x;          // c = 4u+g, 0..1023
    int row = ((c & 3) << 8) + (c >> 2);             // gate*256 + unit (validated)
    g_bias[c] = ldin(mode, bih, row) + ldin(mode, bhh, row);
    const size_t base = (size_t)row * H_;
    float m = 0.0f;
    for (int k = 0; k < H_; ++k) m = fmaxf(m, fabsf(ldin(mode, src, base + k)));
    float inv = (m > 0.0f) ? 127.0f / m : 0.0f;
    g_wscale[c] = m / (127.0f * 127.0f);             // w-scale * h-scale(1/127)
    for (int j = 0; j < 64; ++j) {
        u32 pk = 0;
#pragma unroll
        for (int i = 0; i < 4; ++i) {
            int q = (int)rintf(ldin(mode, src, base + 4 * j + i) * inv);
            q = max(-127, min(127, q));
            pk |= ((u32)(q & 0xff)) << (8 * i);
        }
        g_Wi8[(size_t)(c >> 2) * 256 + j * 4 + (c & 3)] = pk;
    }
}

// ---------- K1: fused embedding + input projection (MFMA, 64-row blocks) ----------
// r9 change: 64 output rows per block (2048 blocks, was 16/8192). Each A-frag
// (g_WA tile) is loaded once and reused across 4 row-groups -> 4x less g_WA
// streaming (2.1 GB -> 524 MB L2) and 16 MFMA per 4 A-loads (was 4 per 4).
// Fragment geometry, per-tile summation order, and store addressing are the
// r3/r8-VALIDATED ones -> bitwise-identical g_xg.
__global__ __launch_bounds__(256) void xg_mfma(const void* __restrict__ pw,
                                               const void* __restrict__ Wemb,
                                               const void* __restrict__ bemb) {
    const int mode = g_mode;
    const int t = threadIdx.x;
    const int m0 = blockIdx.x * 64;
    __shared__ float pwS[64][W_ + 2];                // 13.3 KB
    __shared__ float Wl[E_ * 51];                    // 26 KB
    __shared__ __align__(16) u16 embL[64][136];      // 17.4 KB   (total ~56.7 KB)

    for (int i = t; i < E_ * W_; i += 256) {
        int e = i / W_, w = i - e * W_;
        Wl[e * 51 + w] = ldin(mode, Wemb, i);
    }
    for (int i = t; i < 64 * W_; i += 256) {
        int r = i / W_, w = i - r * W_;
        pwS[r][w] = ldin(mode, pw, (size_t)(m0 + r) * W_ + w);
    }
    __syncthreads();

    {   // emb: e = t&127 constant per thread; W-row cached in regs (r8-validated)
        const int e = t & 127;
        float wreg[W_];
#pragma unroll
        for (int w = 0; w < W_; ++w) wreg[w] = Wl[e * 51 + w];
        const float bb = ldin(mode, bemb, e);
#pragma unroll
        for (int i = 0; i < 32; ++i) {
            const int r = i * 2 + (t >> 7);          // covers all 64 rows x 128 cols
            float a = bb;
#pragma unroll
            for (int w = 0; w < W_; ++w) a = fmaf(pwS[r][w], wreg[w], a);
            embL[r][e] = f2b(fmaxf(a, 0.0f));
        }
    }
    __syncthreads();

    const int l = t & 63;
    const int wv = t >> 6;                           // wave id 0..3 -> 256 c-cols each
    const int lr = l & 15;                           // B-col / D-col within tile
    const int lh = l >> 4;
    // B-frags for 4 row-groups x 4 k-slices (validated layout), 64 VGPRs
    short8 Bf[4][4];
#pragma unroll
    for (int rg = 0; rg < 4; ++rg)
#pragma unroll
        for (int ks = 0; ks < 4; ++ks)
            Bf[rg][ks] = *(const short8*)&embL[rg * 16 + lr][ks * 32 + lh * 8];

    const short8* wa = (const short8*)g_WA;
#pragma unroll 2
    for (int tt = 0; tt < 16; ++tt) {
        const int ct = wv * 16 + tt;                 // c-tile index 0..63
        const int cbase = ct * 16;
        const short8 A0 = wa[(ct * 4 + 0) * 64 + l];
        const short8 A1 = wa[(ct * 4 + 1) * 64 + l];
        const short8 A2 = wa[(ct * 4 + 2) * 64 + l];
        const short8 A3 = wa[(ct * 4 + 3) * 64 + l];
        const float4 bv = *(const float4*)(g_bias + cbase + 4 * lh);
#pragma unroll
        for (int rg = 0; rg < 4; ++rg) {
            f32x4 acc = {bv.x, bv.y, bv.z, bv.w};
            acc = __builtin_amdgcn_mfma_f32_16x16x32_bf16(A0, Bf[rg][0], acc, 0, 0, 0);
            acc = __builtin_amdgcn_mfma_f32_16x16x32_bf16(A1, Bf[rg][1], acc, 0, 0, 0);
            acc = __builtin_amdgcn_mfma_f32_16x16x32_bf16(A2, Bf[rg][2], acc, 0, 0, 0);
            acc = __builtin_amdgcn_mfma_f32_16x16x32_bf16(A3, Bf[rg][3], acc, 0, 0, 0);
            u32 p0 = (u32)f2b(acc[0]) | ((u32)f2b(acc[1]) << 16);
            u32 p1 = (u32)f2b(acc[2]) | ((u32)f2b(acc[3]) << 16);
            uint2 pv; pv.x = p0; pv.y = p1;
            *(uint2*)(g_xg + (size_t)(m0 + rg * 16 + lr) * G_ + cbase + 4 * lh) = pv;
        }
    }
}

// ---------- K2: recurrence, split-K pairs (512 thr, 8 waves, 2 waves/EU) ----------
// r3-VALIDATED VERBATIM (2087-2110us): 4-step unrolled body (fits L1I), rolling
// single-buffer xq prefetch (distance 4), raw lgkmcnt-only barriers, ds_write_b8
// publish, fire-and-forget h store.
__global__ __launch_bounds__(512)
__attribute__((amdgpu_waves_per_eu(2, 2)))
void lstm_split(const void* __restrict__ h0, const void* __restrict__ c0) {
    const int mode = g_mode;
    const int t = threadIdx.x;
    const int b = blockIdx.x;
    const int u = t >> 1;
    const int half = t & 1;

    __shared__ __align__(16) u32 h8[2][H_ / 4];  // double-buffered h (i8), 2x256 B

    // --- 32 weight quads into named v4u via asm (validated pattern, waitcnt per block) ---
    v4u W00, W01, W02, W03, W04, W05, W06, W07, W08, W09, W10, W11, W12, W13, W14, W15;
    v4u W16, W17, W18, W19, W20, W21, W22, W23, W24, W25, W26, W27, W28, W29, W30, W31;
    {
        const u32* wp = g_Wi8 + (size_t)t * 128;   // = u*256 + half*128
        asm volatile(
            "global_load_dwordx4 %0, %16, off\n\t"
            "global_load_dwordx4 %1, %16, off offset:16\n\t"
            "global_load_dwordx4 %2, %16, off offset:32\n\t"
            "global_load_dwordx4 %3, %16, off offset:48\n\t"
            "global_load_dwordx4 %4, %16, off offset:64\n\t"
            "global_load_dwordx4 %5, %16, off offset:80\n\t"
            "global_load_dwordx4 %6, %16, off offset:96\n\t"
            "global_load_dwordx4 %7, %16, off offset:112\n\t"
            "global_load_dwordx4 %8, %16, off offset:128\n\t"
            "global_load_dwordx4 %9, %16, off offset:144\n\t"
            "global_load_dwordx4 %10, %16, off offset:160\n\t"
            "global_load_dwordx4 %11, %16, off offset:176\n\t"
            "global_load_dwordx4 %12, %16, off offset:192\n\t"
            "global_load_dwordx4 %13, %16, off offset:208\n\t"
            "global_load_dwordx4 %14, %16, off offset:224\n\t"
            "global_load_dwordx4 %15, %16, off offset:240\n\t"
            "s_waitcnt vmcnt(0)"
            : "=&v"(W00), "=&v"(W01), "=&v"(W02), "=&v"(W03),
              "=&v"(W04), "=&v"(W05), "=&v"(W06), "=&v"(W07),
              "=&v"(W08), "=&v"(W09), "=&v"(W10), "=&v"(W11),
              "=&v"(W12), "=&v"(W13), "=&v"(W14), "=&v"(W15)
            : "v"(wp));
        asm volatile(
            "global_load_dwordx4 %0, %16, off offset:256\n\t"
            "global_load_dwordx4 %1, %16, off offset:272\n\t"
            "global_load_dwordx4 %2, %16, off offset:288\n\t"
            "global_load_dwordx4 %3, %16, off offset:304\n\t"
            "global_load_dwordx4 %4, %16, off offset:320\n\t"
            "global_load_dwordx4 %5, %16, off offset:336\n\t"
            "global_load_dwordx4 %6, %16, off offset:352\n\t"
            "global_load_dwordx4 %7, %16, off offset:368\n\t"
            "global_load_dwordx4 %8, %16, off offset:384\n\t"
            "global_load_dwordx4 %9, %16, off offset:400\n\t"
            "global_load_dwordx4 %10, %16, off offset:416\n\t"
            "global_load_dwordx4 %11, %16, off offset:432\n\t"
            "global_load_dwordx4 %12, %16, off offset:448\n\t"
            "global_load_dwordx4 %13, %16, off offset:464\n\t"
            "global_load_dwordx4 %14, %16, off offset:480\n\t"
            "global_load_dwordx4 %15, %16, off offset:496\n\t"
            "s_waitcnt vmcnt(0)"
            : "=&v"(W16), "=&v"(W17), "=&v"(W18), "=&v"(W19),
              "=&v"(W20), "=&v"(W21), "=&v"(W22), "=&v"(W23),
              "=&v"(W24), "=&v"(W25), "=&v"(W26), "=&v"(W27),
              "=&v"(W28), "=&v"(W29), "=&v"(W30), "=&v"(W31)
            : "v"(wp));
    }

    const float4 wsc4 = *(const float4*)(g_wscale + 4 * u);
    float c_reg = (half == 0) ? ldin(mode, c0, (size_t)b * H_ + u) : 0.0f;

    if (t < H_ / 4) {
        u32 pk = 0;
#pragma unroll
        for (int i = 0; i < 4; ++i) {
            float h = ldin(mode, h0, (size_t)b * H_ + 4 * t + i);
            int q = (int)rintf(fminf(fmaxf(h, -1.0f), 1.0f) * 127.0f);
            pk |= ((u32)(q & 0xff)) << (8 * i);
        }
        h8[0][t] = pk;
    }
    const u16* xp = g_xg + (size_t)b * S_ * G_ + 4 * u;
    float* hsp = g_hs + (size_t)b * S_ * H_ + u;

    // prime rolling prefetch buffer (all lanes load; odd lanes' copies unused but
    // same cache lines -> no extra traffic, no divergence)
    ushort4 xq[4];
#pragma unroll
    for (int e = 0; e < 4; ++e)
        xq[e] = *(const ushort4*)(xp + (size_t)e * G_);

    asm volatile("s_waitcnt lgkmcnt(0)\n\t"
                 "s_barrier" ::: "memory");

#define DOTG(HV, WA, WB, WC, WD)                                              \
            ai = dot4i8(HV.x, WA.x, ai); af = dot4i8(HV.x, WA.y, af);         \
            ag = dot4i8(HV.x, WA.z, ag); ao = dot4i8(HV.x, WA.w, ao);         \
            ai = dot4i8(HV.y, WB.x, ai); af = dot4i8(HV.y, WB.y, af);         \
            ag = dot4i8(HV.y, WB.z, ag); ao = dot4i8(HV.y, WB.w, ao);         \
            ai = dot4i8(HV.z, WC.x, ai); af = dot4i8(HV.z, WC.y, af);         \
            ag = dot4i8(HV.z, WC.z, ag); ao = dot4i8(HV.z, WC.w, ao);         \
            ai = dot4i8(HV.w, WD.x, ai); af = dot4i8(HV.w, WD.y, af);         \
            ag = dot4i8(HV.w, WD.z, ag); ao = dot4i8(HV.w, WD.w, ao);

    for (int s0 = 0; s0 < S_; s0 += 4) {
#pragma unroll
        for (int e = 0; e < 4; ++e) {
            const int s = s0 + e;
            // consume current xq, immediately re-issue for s+4 (rolling prefetch)
            const ushort4 xv = xq[e];
            const int sn = (s + 4 < S_) ? s + 4 : s;
            xq[e] = *(const ushort4*)(xp + (size_t)sn * G_);

            const uint4* hp = (const uint4*)h8[s & 1] + half * 8;
            uint4 h0v = hp[0], h1v = hp[1], h2v = hp[2], h3v = hp[3];
            uint4 h4v = hp[4], h5v = hp[5], h6v = hp[6], h7v = hp[7];

            int ai = 0, af = 0, ag = 0, ao = 0;
            DOTG(h0v, W00, W01, W02, W03)
            DOTG(h1v, W04, W05, W06, W07)
            DOTG(h2v, W08, W09, W10, W11)
            DOTG(h3v, W12, W13, W14, W15)
            DOTG(h4v, W16, W17, W18, W19)
            DOTG(h5v, W20, W21, W22, W23)
            DOTG(h6v, W24, W25, W26, W27)
            DOTG(h7v, W28, W29, W30, W31)

            ai += __shfl_xor(ai, 1, 64);
            af += __shfl_xor(af, 1, 64);
            ag += __shfl_xor(ag, 1, 64);
            ao += __shfl_xor(ao, 1, 64);

            if (half == 0) {
                float gi = (float)ai * wsc4.x + b2f(xv.x);
                float gf = (float)af * wsc4.y + b2f(xv.y);
                float gg = (float)ag * wsc4.z + b2f(xv.z);
                float go = (float)ao * wsc4.w + b2f(xv.w);
                float ii = sigmoidf_(clamp30(gi));
                float ff = sigmoidf_(clamp30(gf));
                float gv = tanhf_(clamp30(gg));
                float oo = sigmoidf_(clamp30(go));
                c_reg = fmaf(ff, c_reg, ii * gv);
                float h = oo * tanhf_(c_reg);
                int q = (int)rintf(fminf(fmaxf(h, -1.0f), 1.0f) * 127.0f) & 0xff;
                ((u8*)h8[(s + 1) & 1])[u] = (u8)q;   // single-byte publish
                hsp[(size_t)s * H_] = h;             // fire-and-forget
            }
            // LDS ordering only; global loads/stores stay in flight
            asm volatile("s_waitcnt lgkmcnt(0)\n\t"
                         "s_barrier" ::: "memory");
        }
    }
#undef DOTG
}

// ---------- K3: output head — one wave per (s,b), fp32 h ----------
__global__ __launch_bounds__(256) void head_kernel(const void* __restrict__ Wout,
                                                   const void* __restrict__ bout,
                                                   void* __restrict__ yv) {
    const int mode = g_mode;
    const int t = threadIdx.x;
    const int idx = blockIdx.x * 4 + (t >> 6);   // (s,b) pair
    const int l = t & 63;
    const int s = idx >> 6, b = idx & 63;
    const float* hb = g_hs + ((size_t)b * S_ + s) * H_ + 4 * l;
    float4 hv = *(const float4*)hb;
    float p = hv.x * ldin(mode, Wout, 4 * l + 0)
            + hv.y * ldin(mode, Wout, 4 * l + 1)
            + hv.z * ldin(mode, Wout, 4 * l + 2)
            + hv.w * ldin(mode, Wout, 4 * l + 3);
#pragma unroll
    for (int off = 32; off > 0; off >>= 1) p += __shfl_down(p, off, 64);
    if (l == 0) {
        float yf = sigmoidf_(clamp30(p + ldin(mode, bout, 0)));
        if (mode) ((float*)yv)[(size_t)s * B_ + b] = yf;
        else      ((u16*)yv)[(size_t)s * B_ + b] = f2b(yf);
    }
}

extern "C" void kernel_launch(void* const* d_in, const int* in_sizes, int n_in,
                              void* d_out, int out_size, void* d_ws, size_t ws_size,
                              hipStream_t stream) {
    const void* pw   = d_in[0];   // [B,S,50]
    const void* Wemb = d_in[1];   // [E,50]
    const void* bemb = d_in[2];   // [E]
    const void* Wih  = d_in[3];   // [G,E]
    const void* Whh  = d_in[4];   // [G,H]
    const void* bih  = d_in[5];   // [G]
    const void* bhh  = d_in[6];   // [G]
    const void* Wout = d_in[7];   // [1,H]
    const void* bout = d_in[8];   // [1]
    const void* h0   = d_in[9];   // [B,H]
    const void* c0   = d_in[10];  // [B,H]
    void* y = d_out;              // [S,B]
    (void)d_ws; (void)ws_size;

    sniff_kernel<<<1, 1, 0, stream>>>((const u16*)Wemb);
    prep_wa<<<(E_ * G_) / 256, 256, 0, stream>>>(Wih);
    prep_wi8<<<G_ / 256, 256, 0, stream>>>(Whh, bih, bhh);
    xg_mfma<<<(B_ * S_) / 64, 256, 0, stream>>>(pw, Wemb, bemb);
    lstm_split<<<B_, 512, 0, stream>>>(h0, c0);
    head_kernel<<<(S_ * B_) / 4, 256, 0, stream>>>(Wout, bout, y);
}

// Round 10
// 2119.032 us; speedup vs baseline: 1.8781x; 1.1700x over previous
//
#include <hip/hip_runtime.h>
#include <hip/hip_bf16.h>

// B=64, S=2048, WIN=50, E=128, H=256, G=4H=1024.
#define B_ 64
#define S_ 2048
#define W_ 50
#define E_ 128
#define H_ 256
#define G_ 1024

typedef unsigned short u16;
typedef unsigned int u32;
typedef unsigned char u8;
typedef unsigned int v4u __attribute__((ext_vector_type(4)));
typedef __attribute__((ext_vector_type(8))) short short8;   // bf16x8 MFMA frag
typedef __attribute__((ext_vector_type(4))) float f32x4;    // MFMA acc

// Module-global scratch (BSS; d_ws untrusted).
__device__ int g_mode;                          // 0 = bf16 buffers, 1 = fp32 buffers
__device__ u16 g_WA[E_ * G_];                   // Wih in MFMA A-frag order (bf16) [r3-validated]
__device__ float g_bias[G_];                    // bih+bhh, gate-interleaved c = 4u+q
__device__ u32 g_Wi8[G_ * 64];                  // [u][j][g]: pack4(Whh col c=4u+g, k=4j..4j+3)
__device__ float g_wscale[G_];                  // per-column dequant: max|W[:,c]| /(127*127), c=4u+g
__device__ u16 g_xg[(size_t)B_ * S_ * G_];      // [b][s][1024] bf16, biases folded (validated)
__device__ float g_hs[(size_t)B_ * S_ * H_];    // [b][s][u] fp32 hidden states (for output head)

__device__ __forceinline__ float b2f(u16 u) {
    union { u32 i; float f; } v;
    v.i = ((u32)u) << 16;
    return v.f;
}
__device__ __forceinline__ u16 f2b(float f) {
    __hip_bfloat16 h = __float2bfloat16(f);
    return *reinterpret_cast<u16*>(&h);
}
__device__ __forceinline__ float ldin(int mode, const void* p, size_t i) {
    return mode ? ((const float*)p)[i] : b2f(((const u16*)p)[i]);
}
__device__ __forceinline__ float clamp30(float x) {
    return fminf(fmaxf(x, -30.0f), 30.0f);
}
__device__ __forceinline__ float sigmoidf_(float x) { return 1.0f / (1.0f + __expf(-x)); }
__device__ __forceinline__ float tanhf_(float x) {
    float e = __expf(2.0f * x);
    return 1.0f - 2.0f / (e + 1.0f);
}
// Fast forms for the lstm hot loop ONLY: v_rcp_f32 (<=1 ulp) replaces the ~9-instr
// IEEE divide chain. rcp(inf)=0 gives exact saturation -> no clamp needed:
//   x->-inf: exp(-x)=inf -> rcp=0  (sigmoid->0);  x->+inf: exp(-x)=0 -> rcp(1)=1.
//   tanh:    exp(2x)=inf -> 1-2*0=1;              exp(2x)=0 -> 1-2*1 = -1.
__device__ __forceinline__ float fastrcp(float x) {
    float r;
    asm("v_rcp_f32 %0, %1" : "=v"(r) : "v"(x));
    return r;
}
__device__ __forceinline__ float fsig(float x) { return fastrcp(1.0f + __expf(-x)); }
__device__ __forceinline__ float ftanh(float x) {
    return fmaf(-2.0f, fastrcp(1.0f + __expf(2.0f * x)), 1.0f);
}
__device__ __forceinline__ int dot4i8(u32 a, u32 b, int acc) {
#if __has_builtin(__builtin_amdgcn_sdot4)
    return __builtin_amdgcn_sdot4(a, b, acc, false);
#else
    acc += (int)(signed char)(a)       * (int)(signed char)(b);
    acc += (int)(signed char)(a >> 8)  * (int)(signed char)(b >> 8);
    acc += (int)(signed char)(a >> 16) * (int)(signed char)(b >> 16);
    acc += (int)(signed char)(a >> 24) * (int)(signed char)(b >> 24);
    return acc;
#endif
}

// ---------- K0: dtype sniffer (validated) ----------
__global__ void sniff_kernel(const u16* __restrict__ wemb) {
    int sane = 0;
    for (int i = 0; i < 2048; ++i) {
        int ex = (wemb[i] >> 7) & 0xFF;
        if (ex == 0 || (ex >= 96 && ex <= 143)) ++sane;
    }
    g_mode = (sane >= 1900) ? 0 : 1;
}

// ---------- K0b: Wih -> MFMA A-fragment order (r3-validated) ----------
__global__ __launch_bounds__(256) void prep_wa(const void* __restrict__ src) {
    const int mode = g_mode;
    int i = blockIdx.x * 256 + threadIdx.x;          // dst flat index, 0..131071
    int j = i & 7, l = (i >> 3) & 63, ks = (i >> 9) & 3, ct = i >> 11;
    int c = ct * 16 + (l & 15);
    int e = ks * 32 + (l >> 4) * 8 + j;
    int row = ((c & 3) << 8) + (c >> 2);
    g_WA[i] = f2b(ldin(mode, src, (size_t)row * E_ + e));
}

// ---------- K0c: Whh -> int8, unit-major quad layout [u][j][g]; + gate biases ----------
__global__ __launch_bounds__(256) void prep_wi8(const void* __restrict__ src,
                                                const void* __restrict__ bih,
                                                const void* __restrict__ bhh) {
    const int mode = g_mode;
    int c = blockIdx.x * 256 + threadIdx.x;          // c = 4u+g, 0..1023
    int row = ((c & 3) << 8) + (c >> 2);             // gate*256 + unit (validated)
    g_bias[c] = ldin(mode, bih, row) + ldin(mode, bhh, row);
    const size_t base = (size_t)row * H_;
    float m = 0.0f;
    for (int k = 0; k < H_; ++k) m = fmaxf(m, fabsf(ldin(mode, src, base + k)));
    float inv = (m > 0.0f) ? 127.0f / m : 0.0f;
    g_wscale[c] = m / (127.0f * 127.0f);             // w-scale * h-scale(1/127)
    for (int j = 0; j < 64; ++j) {
        u32 pk = 0;
#pragma unroll
        for (int i = 0; i < 4; ++i) {
            int q = (int)rintf(ldin(mode, src, base + 4 * j + i) * inv);
            q = max(-127, min(127, q));
            pk |= ((u32)(q & 0xff)) << (8 * i);
        }
        g_Wi8[(size_t)(c >> 2) * 256 + j * 4 + (c & 3)] = pk;
    }
}

// ---------- K1: fused embedding + input projection (MFMA, 64-row blocks, r9-validated) ----------
__global__ __launch_bounds__(256) void xg_mfma(const void* __restrict__ pw,
                                               const void* __restrict__ Wemb,
                                               const void* __restrict__ bemb) {
    const int mode = g_mode;
    const int t = threadIdx.x;
    const int m0 = blockIdx.x * 64;
    __shared__ float pwS[64][W_ + 2];                // 13.3 KB
    __shared__ float Wl[E_ * 51];                    // 26 KB
    __shared__ __align__(16) u16 embL[64][136];      // 17.4 KB   (total ~56.7 KB)

    for (int i = t; i < E_ * W_; i += 256) {
        int e = i / W_, w = i - e * W_;
        Wl[e * 51 + w] = ldin(mode, Wemb, i);
    }
    for (int i = t; i < 64 * W_; i += 256) {
        int r = i / W_, w = i - r * W_;
        pwS[r][w] = ldin(mode, pw, (size_t)(m0 + r) * W_ + w);
    }
    __syncthreads();

    {   // emb: e = t&127 constant per thread; W-row cached in regs (r8-validated)
        const int e = t & 127;
        float wreg[W_];
#pragma unroll
        for (int w = 0; w < W_; ++w) wreg[w] = Wl[e * 51 + w];
        const float bb = ldin(mode, bemb, e);
#pragma unroll
        for (int i = 0; i < 32; ++i) {
            const int r = i * 2 + (t >> 7);          // covers all 64 rows x 128 cols
            float a = bb;
#pragma unroll
            for (int w = 0; w < W_; ++w) a = fmaf(pwS[r][w], wreg[w], a);
            embL[r][e] = f2b(fmaxf(a, 0.0f));
        }
    }
    __syncthreads();

    const int l = t & 63;
    const int wv = t >> 6;                           // wave id 0..3 -> 256 c-cols each
    const int lr = l & 15;                           // B-col / D-col within tile
    const int lh = l >> 4;
    short8 Bf[4][4];
#pragma unroll
    for (int rg = 0; rg < 4; ++rg)
#pragma unroll
        for (int ks = 0; ks < 4; ++ks)
            Bf[rg][ks] = *(const short8*)&embL[rg * 16 + lr][ks * 32 + lh * 8];

    const short8* wa = (const short8*)g_WA;
#pragma unroll 2
    for (int tt = 0; tt < 16; ++tt) {
        const int ct = wv * 16 + tt;                 // c-tile index 0..63
        const int cbase = ct * 16;
        const short8 A0 = wa[(ct * 4 + 0) * 64 + l];
        const short8 A1 = wa[(ct * 4 + 1) * 64 + l];
        const short8 A2 = wa[(ct * 4 + 2) * 64 + l];
        const short8 A3 = wa[(ct * 4 + 3) * 64 + l];
        const float4 bv = *(const float4*)(g_bias + cbase + 4 * lh);
#pragma unroll
        for (int rg = 0; rg < 4; ++rg) {
            f32x4 acc = {bv.x, bv.y, bv.z, bv.w};
            acc = __builtin_amdgcn_mfma_f32_16x16x32_bf16(A0, Bf[rg][0], acc, 0, 0, 0);
            acc = __builtin_amdgcn_mfma_f32_16x16x32_bf16(A1, Bf[rg][1], acc, 0, 0, 0);
            acc = __builtin_amdgcn_mfma_f32_16x16x32_bf16(A2, Bf[rg][2], acc, 0, 0, 0);
            acc = __builtin_amdgcn_mfma_f32_16x16x32_bf16(A3, Bf[rg][3], acc, 0, 0, 0);
            u32 p0 = (u32)f2b(acc[0]) | ((u32)f2b(acc[1]) << 16);
            u32 p1 = (u32)f2b(acc[2]) | ((u32)f2b(acc[3]) << 16);
            uint2 pv; pv.x = p0; pv.y = p1;
            *(uint2*)(g_xg + (size_t)(m0 + rg * 16 + lr) * G_ + cbase + 4 * lh) = pv;
        }
    }
}

// ---------- K2: recurrence, split-K pairs (512 thr, 8 waves, 2 waves/EU) ----------
// r3/r9-validated skeleton. r10 change (ACT only): fast sigmoid/tanh via v_rcp_f32
// (5 IEEE divide chains ~9 instrs each -> 5 rcp) and clamp30 removed (rcp form
// saturates exactly at +-inf). Shortens the serial post-dot tail each step.
__global__ __launch_bounds__(512)
__attribute__((amdgpu_waves_per_eu(2, 2)))
void lstm_split(const void* __restrict__ h0, const void* __restrict__ c0) {
    const int mode = g_mode;
    const int t = threadIdx.x;
    const int b = blockIdx.x;
    const int u = t >> 1;
    const int half = t & 1;

    __shared__ __align__(16) u32 h8[2][H_ / 4];  // double-buffered h (i8), 2x256 B

    // --- 32 weight quads into named v4u via asm (validated pattern, waitcnt per block) ---
    v4u W00, W01, W02, W03, W04, W05, W06, W07, W08, W09, W10, W11, W12, W13, W14, W15;
    v4u W16, W17, W18, W19, W20, W21, W22, W23, W24, W25, W26, W27, W28, W29, W30, W31;
    {
        const u32* wp = g_Wi8 + (size_t)t * 128;   // = u*256 + half*128
        asm volatile(
            "global_load_dwordx4 %0, %16, off\n\t"
            "global_load_dwordx4 %1, %16, off offset:16\n\t"
            "global_load_dwordx4 %2, %16, off offset:32\n\t"
            "global_load_dwordx4 %3, %16, off offset:48\n\t"
            "global_load_dwordx4 %4, %16, off offset:64\n\t"
            "global_load_dwordx4 %5, %16, off offset:80\n\t"
            "global_load_dwordx4 %6, %16, off offset:96\n\t"
            "global_load_dwordx4 %7, %16, off offset:112\n\t"
            "global_load_dwordx4 %8, %16, off offset:128\n\t"
            "global_load_dwordx4 %9, %16, off offset:144\n\t"
            "global_load_dwordx4 %10, %16, off offset:160\n\t"
            "global_load_dwordx4 %11, %16, off offset:176\n\t"
            "global_load_dwordx4 %12, %16, off offset:192\n\t"
            "global_load_dwordx4 %13, %16, off offset:208\n\t"
            "global_load_dwordx4 %14, %16, off offset:224\n\t"
            "global_load_dwordx4 %15, %16, off offset:240\n\t"
            "s_waitcnt vmcnt(0)"
            : "=&v"(W00), "=&v"(W01), "=&v"(W02), "=&v"(W03),
              "=&v"(W04), "=&v"(W05), "=&v"(W06), "=&v"(W07),
              "=&v"(W08), "=&v"(W09), "=&v"(W10), "=&v"(W11),
              "=&v"(W12), "=&v"(W13), "=&v"(W14), "=&v"(W15)
            : "v"(wp));
        asm volatile(
            "global_load_dwordx4 %0, %16, off offset:256\n\t"
            "global_load_dwordx4 %1, %16, off offset:272\n\t"
            "global_load_dwordx4 %2, %16, off offset:288\n\t"
            "global_load_dwordx4 %3, %16, off offset:304\n\t"
            "global_load_dwordx4 %4, %16, off offset:320\n\t"
            "global_load_dwordx4 %5, %16, off offset:336\n\t"
            "global_load_dwordx4 %6, %16, off offset:352\n\t"
            "global_load_dwordx4 %7, %16, off offset:368\n\t"
            "global_load_dwordx4 %8, %16, off offset:384\n\t"
            "global_load_dwordx4 %9, %16, off offset:400\n\t"
            "global_load_dwordx4 %10, %16, off offset:416\n\t"
            "global_load_dwordx4 %11, %16, off offset:432\n\t"
            "global_load_dwordx4 %12, %16, off offset:448\n\t"
            "global_load_dwordx4 %13, %16, off offset:464\n\t"
            "global_load_dwordx4 %14, %16, off offset:480\n\t"
            "global_load_dwordx4 %15, %16, off offset:496\n\t"
            "s_waitcnt vmcnt(0)"
            : "=&v"(W16), "=&v"(W17), "=&v"(W18), "=&v"(W19),
              "=&v"(W20), "=&v"(W21), "=&v"(W22), "=&v"(W23),
              "=&v"(W24), "=&v"(W25), "=&v"(W26), "=&v"(W27),
              "=&v"(W28), "=&v"(W29), "=&v"(W30), "=&v"(W31)
            : "v"(wp));
    }

    const float4 wsc4 = *(const float4*)(g_wscale + 4 * u);
    float c_reg = (half == 0) ? ldin(mode, c0, (size_t)b * H_ + u) : 0.0f;

    if (t < H_ / 4) {
        u32 pk = 0;
#pragma unroll
        for (int i = 0; i < 4; ++i) {
            float h = ldin(mode, h0, (size_t)b * H_ + 4 * t + i);
            int q = (int)rintf(fminf(fmaxf(h, -1.0f), 1.0f) * 127.0f);
            pk |= ((u32)(q & 0xff)) << (8 * i);
        }
        h8[0][t] = pk;
    }
    const u16* xp = g_xg + (size_t)b * S_ * G_ + 4 * u;
    float* hsp = g_hs + (size_t)b * S_ * H_ + u;

    // prime rolling prefetch buffer (all lanes load; odd lanes' copies unused but
    // same cache lines -> no extra traffic, no divergence)
    ushort4 xq[4];
#pragma unroll
    for (int e = 0; e < 4; ++e)
        xq[e] = *(const ushort4*)(xp + (size_t)e * G_);

    asm volatile("s_waitcnt lgkmcnt(0)\n\t"
                 "s_barrier" ::: "memory");

#define DOTG(HV, WA, WB, WC, WD)                                              \
            ai = dot4i8(HV.x, WA.x, ai); af = dot4i8(HV.x, WA.y, af);         \
            ag = dot4i8(HV.x, WA.z, ag); ao = dot4i8(HV.x, WA.w, ao);         \
            ai = dot4i8(HV.y, WB.x, ai); af = dot4i8(HV.y, WB.y, af);         \
            ag = dot4i8(HV.y, WB.z, ag); ao = dot4i8(HV.y, WB.w, ao);         \
            ai = dot4i8(HV.z, WC.x, ai); af = dot4i8(HV.z, WC.y, af);         \
            ag = dot4i8(HV.z, WC.z, ag); ao = dot4i8(HV.z, WC.w, ao);         \
            ai = dot4i8(HV.w, WD.x, ai); af = dot4i8(HV.w, WD.y, af);         \
            ag = dot4i8(HV.w, WD.z, ag); ao = dot4i8(HV.w, WD.w, ao);

    for (int s0 = 0; s0 < S_; s0 += 4) {
#pragma unroll
        for (int e = 0; e < 4; ++e) {
            const int s = s0 + e;
            // consume current xq, immediately re-issue for s+4 (rolling prefetch)
            const ushort4 xv = xq[e];
            const int sn = (s + 4 < S_) ? s + 4 : s;
            xq[e] = *(const ushort4*)(xp + (size_t)sn * G_);

            const uint4* hp = (const uint4*)h8[s & 1] + half * 8;
            uint4 h0v = hp[0], h1v = hp[1], h2v = hp[2], h3v = hp[3];
            uint4 h4v = hp[4], h5v = hp[5], h6v = hp[6], h7v = hp[7];

            int ai = 0, af = 0, ag = 0, ao = 0;
            DOTG(h0v, W00, W01, W02, W03)
            DOTG(h1v, W04, W05, W06, W07)
            DOTG(h2v, W08, W09, W10, W11)
            DOTG(h3v, W12, W13, W14, W15)
            DOTG(h4v, W16, W17, W18, W19)
            DOTG(h5v, W20, W21, W22, W23)
            DOTG(h6v, W24, W25, W26, W27)
            DOTG(h7v, W28, W29, W30, W31)

            ai += __shfl_xor(ai, 1, 64);
            af += __shfl_xor(af, 1, 64);
            ag += __shfl_xor(ag, 1, 64);
            ao += __shfl_xor(ao, 1, 64);

            if (half == 0) {
                float gi = (float)ai * wsc4.x + b2f(xv.x);
                float gf = (float)af * wsc4.y + b2f(xv.y);
                float gg = (float)ag * wsc4.z + b2f(xv.z);
                float go = (float)ao * wsc4.w + b2f(xv.w);
                float ii = fsig(gi);
                float ff = fsig(gf);
                float gv = ftanh(gg);
                float oo = fsig(go);
                c_reg = fmaf(ff, c_reg, ii * gv);
                float h = oo * ftanh(c_reg);
                int q = (int)rintf(fminf(fmaxf(h, -1.0f), 1.0f) * 127.0f) & 0xff;
                ((u8*)h8[(s + 1) & 1])[u] = (u8)q;   // single-byte publish
                hsp[(size_t)s * H_] = h;             // fire-and-forget
            }
            // LDS ordering only; global loads/stores stay in flight
            asm volatile("s_waitcnt lgkmcnt(0)\n\t"
                         "s_barrier" ::: "memory");
        }
    }
#undef DOTG
}

// ---------- K3: output head — one wave per (s,b), fp32 h (precise math, unchanged) ----------
__global__ __launch_bounds__(256) void head_kernel(const void* __restrict__ Wout,
                                                   const void* __restrict__ bout,
                                                   void* __restrict__ yv) {
    const int mode = g_mode;
    const int t = threadIdx.x;
    const int idx = blockIdx.x * 4 + (t >> 6);   // (s,b) pair
    const int l = t & 63;
    const int s = idx >> 6, b = idx & 63;
    const float* hb = g_hs + ((size_t)b * S_ + s) * H_ + 4 * l;
    float4 hv = *(const float4*)hb;
    float p = hv.x * ldin(mode, Wout, 4 * l + 0)
            + hv.y * ldin(mode, Wout, 4 * l + 1)
            + hv.z * ldin(mode, Wout, 4 * l + 2)
            + hv.w * ldin(mode, Wout, 4 * l + 3);
#pragma unroll
    for (int off = 32; off > 0; off >>= 1) p += __shfl_down(p, off, 64);
    if (l == 0) {
        float yf = sigmoidf_(clamp30(p + ldin(mode, bout, 0)));
        if (mode) ((float*)yv)[(size_t)s * B_ + b] = yf;
        else      ((u16*)yv)[(size_t)s * B_ + b] = f2b(yf);
    }
}

extern "C" void kernel_launch(void* const* d_in, const int* in_sizes, int n_in,
                              void* d_out, int out_size, void* d_ws, size_t ws_size,
                              hipStream_t stream) {
    const void* pw   = d_in[0];   // [B,S,50]
    const void* Wemb = d_in[1];   // [E,50]
    const void* bemb = d_in[2];   // [E]
    const void* Wih  = d_in[3];   // [G,E]
    const void* Whh  = d_in[4];   // [G,H]
    const void* bih  = d_in[5];   // [G]
    const void* bhh  = d_in[6];   // [G]
    const void* Wout = d_in[7];   // [1,H]
    const void* bout = d_in[8];   // [1]
    const void* h0   = d_in[9];   // [B,H]
    const void* c0   = d_in[10];  // [B,H]
    void* y = d_out;              // [S,B]
    (void)d_ws; (void)ws_size;

    sniff_kernel<<<1, 1, 0, stream>>>((const u16*)Wemb);
    prep_wa<<<(E_ * G_) / 256, 256, 0, stream>>>(Wih);
    prep_wi8<<<G_ / 256, 256, 0, stream>>>(Whh, bih, bhh);
    xg_mfma<<<(B_ * S_) / 64, 256, 0, stream>>>(pw, Wemb, bemb);
    lstm_split<<<B_, 512, 0, stream>>>(h0, c0);
    head_kernel<<<(S_ * B_) / 4, 256, 0, stream>>>(Wout, bout, y);
}

// Round 12
// 2088.560 us; speedup vs baseline: 1.9055x; 1.0146x over previous
//
#include <hip/hip_runtime.h>
#include <hip/hip_bf16.h>

// B=64, S=2048, WIN=50, E=128, H=256, G=4H=1024.
#define B_ 64
#define S_ 2048
#define W_ 50
#define E_ 128
#define H_ 256
#define G_ 1024

typedef unsigned short u16;
typedef unsigned int u32;
typedef unsigned char u8;
typedef unsigned int v4u __attribute__((ext_vector_type(4)));
typedef __attribute__((ext_vector_type(8))) short short8;   // bf16x8 MFMA frag
typedef __attribute__((ext_vector_type(4))) float f32x4;    // MFMA acc

// Module-global scratch (BSS; d_ws untrusted).
__device__ int g_mode;                          // 0 = bf16 buffers, 1 = fp32 buffers
__device__ u16 g_WA[E_ * G_];                   // Wih in MFMA A-frag order (bf16) [r3-validated]
__device__ float g_bias[G_];                    // bih+bhh, gate-interleaved c = 4u+q
__device__ u32 g_Wi8[G_ * 64];                  // [u][j][g]: pack4(Whh col c=4u+g, k=4j..4j+3)
__device__ float g_wscale[G_];                  // per-column dequant: max|W[:,c]| /(127*127), c=4u+g
__device__ u16 g_xg[(size_t)B_ * S_ * G_];      // [b][s][1024] bf16, biases folded (validated)
__device__ float g_hs[(size_t)B_ * S_ * H_];    // [b][s][u] fp32 hidden states (for output head)

__device__ __forceinline__ float b2f(u16 u) {
    union { u32 i; float f; } v;
    v.i = ((u32)u) << 16;
    return v.f;
}
__device__ __forceinline__ u16 f2b(float f) {
    __hip_bfloat16 h = __float2bfloat16(f);
    return *reinterpret_cast<u16*>(&h);
}
__device__ __forceinline__ float ldin(int mode, const void* p, size_t i) {
    return mode ? ((const float*)p)[i] : b2f(((const u16*)p)[i]);
}
__device__ __forceinline__ float clamp30(float x) {
    return fminf(fmaxf(x, -30.0f), 30.0f);
}
__device__ __forceinline__ float sigmoidf_(float x) { return 1.0f / (1.0f + __expf(-x)); }
__device__ __forceinline__ float tanhf_(float x) {
    float e = __expf(2.0f * x);
    return 1.0f - 2.0f / (e + 1.0f);
}
// Fast forms for the lstm hot loop ONLY (r10-validated): v_rcp_f32 (<=1 ulp)
// replaces the IEEE divide chain; rcp(inf)=0 gives exact saturation -> no clamp.
__device__ __forceinline__ float fastrcp(float x) {
    float r;
    asm("v_rcp_f32 %0, %1" : "=v"(r) : "v"(x));
    return r;
}
__device__ __forceinline__ float fsig(float x) { return fastrcp(1.0f + __expf(-x)); }
__device__ __forceinline__ float ftanh(float x) {
    return fmaf(-2.0f, fastrcp(1.0f + __expf(2.0f * x)), 1.0f);
}
// r11: lane^1 pair-combine as VALU DPP (quad_perm [1,0,3,2] = ctrl 0xB1) instead of
// DS-pipe shfl_xor — removes ~50-80cy of DS latency from the per-step serial tail.
// Integer add order unchanged -> bit-identical to shfl_xor version.
__device__ __forceinline__ int dppadd1(int x) {
    return x + __builtin_amdgcn_update_dpp(0, x, 0xB1, 0xF, 0xF, true);
}
__device__ __forceinline__ int dot4i8(u32 a, u32 b, int acc) {
#if __has_builtin(__builtin_amdgcn_sdot4)
    return __builtin_amdgcn_sdot4(a, b, acc, false);
#else
    acc += (int)(signed char)(a)       * (int)(signed char)(b);
    acc += (int)(signed char)(a >> 8)  * (int)(signed char)(b >> 8);
    acc += (int)(signed char)(a >> 16) * (int)(signed char)(b >> 16);
    acc += (int)(signed char)(a >> 24) * (int)(signed char)(b >> 24);
    return acc;
#endif
}

// ---------- K0: dtype sniffer (validated) ----------
__global__ void sniff_kernel(const u16* __restrict__ wemb) {
    int sane = 0;
    for (int i = 0; i < 2048; ++i) {
        int ex = (wemb[i] >> 7) & 0xFF;
        if (ex == 0 || (ex >= 96 && ex <= 143)) ++sane;
    }
    g_mode = (sane >= 1900) ? 0 : 1;
}

// ---------- K0b: Wih -> MFMA A-fragment order (r3-validated) ----------
__global__ __launch_bounds__(256) void prep_wa(const void* __restrict__ src) {
    const int mode = g_mode;
    int i = blockIdx.x * 256 + threadIdx.x;          // dst flat index, 0..131071
    int j = i & 7, l = (i >> 3) & 63, ks = (i >> 9) & 3, ct = i >> 11;
    int c = ct * 16 + (l & 15);
    int e = ks * 32 + (l >> 4) * 8 + j;
    int row = ((c & 3) << 8) + (c >> 2);
    g_WA[i] = f2b(ldin(mode, src, (size_t)row * E_ + e));
}

// ---------- K0c: Whh -> int8, unit-major quad layout [u][j][g]; + gate biases ----------
__global__ __launch_bounds__(256) void prep_wi8(const void* __restrict__ src,
                                                const void* __restrict__ bih,
                                                const void* __restrict__ bhh) {
    const int mode = g_mode;
    int c = blockIdx.x * 256 + threadIdx.x;          // c = 4u+g, 0..1023
    int row = ((c & 3) << 8) + (c >> 2);             // gate*256 + unit (validated)
    g_bias[c] = ldin(mode, bih, row) + ldin(mode, bhh, row);
    const size_t base = (size_t)row * H_;
    float m = 0.0f;
    for (int k = 0; k < H_; ++k) m = fmaxf(m, fabsf(ldin(mode, src, base + k)));
    float inv = (m > 0.0f) ? 127.0f / m : 0.0f;
    g_wscale[c] = m / (127.0f * 127.0f);             // w-scale * h-scale(1/127)
    for (int j = 0; j < 64; ++j) {
        u32 pk = 0;
#pragma unroll
        for (int i = 0; i < 4; ++i) {
            int q = (int)rintf(ldin(mode, src, base + 4 * j + i) * inv);
            q = max(-127, min(127, q));
            pk |= ((u32)(q & 0xff)) << (8 * i);
        }
        g_Wi8[(size_t)(c >> 2) * 256 + j * 4 + (c & 3)] = pk;
    }
}

// ---------- K1: fused embedding + input projection (MFMA, 64-row blocks, r9-validated) ----------
__global__ __launch_bounds__(256) void xg_mfma(const void* __restrict__ pw,
                                               const void* __restrict__ Wemb,
                                               const void* __restrict__ bemb) {
    const int mode = g_mode;
    const int t = threadIdx.x;
    const int m0 = blockIdx.x * 64;
    __shared__ float pwS[64][W_ + 2];                // 13.3 KB
    __shared__ float Wl[E_ * 51];                    // 26 KB
    __shared__ __align__(16) u16 embL[64][136];      // 17.4 KB   (total ~56.7 KB)

    for (int i = t; i < E_ * W_; i += 256) {
        int e = i / W_, w = i - e * W_;
        Wl[e * 51 + w] = ldin(mode, Wemb, i);
    }
    for (int i = t; i < 64 * W_; i += 256) {
        int r = i / W_, w = i - r * W_;
        pwS[r][w] = ldin(mode, pw, (size_t)(m0 + r) * W_ + w);
    }
    __syncthreads();

    {   // emb: e = t&127 constant per thread; W-row cached in regs (r8-validated)
        const int e = t & 127;
        float wreg[W_];
#pragma unroll
        for (int w = 0; w < W_; ++w) wreg[w] = Wl[e * 51 + w];
        const float bb = ldin(mode, bemb, e);
#pragma unroll
        for (int i = 0; i < 32; ++i) {
            const int r = i * 2 + (t >> 7);          // covers all 64 rows x 128 cols
            float a = bb;
#pragma unroll
            for (int w = 0; w < W_; ++w) a = fmaf(pwS[r][w], wreg[w], a);
            embL[r][e] = f2b(fmaxf(a, 0.0f));
        }
    }
    __syncthreads();

    const int l = t & 63;
    const int wv = t >> 6;                           // wave id 0..3 -> 256 c-cols each
    const int lr = l & 15;                           // B-col / D-col within tile
    const int lh = l >> 4;
    short8 Bf[4][4];
#pragma unroll
    for (int rg = 0; rg < 4; ++rg)
#pragma unroll
        for (int ks = 0; ks < 4; ++ks)
            Bf[rg][ks] = *(const short8*)&embL[rg * 16 + lr][ks * 32 + lh * 8];

    const short8* wa = (const short8*)g_WA;
#pragma unroll 2
    for (int tt = 0; tt < 16; ++tt) {
        const int ct = wv * 16 + tt;                 // c-tile index 0..63
        const int cbase = ct * 16;
        const short8 A0 = wa[(ct * 4 + 0) * 64 + l];
        const short8 A1 = wa[(ct * 4 + 1) * 64 + l];
        const short8 A2 = wa[(ct * 4 + 2) * 64 + l];
        const short8 A3 = wa[(ct * 4 + 3) * 64 + l];
        const float4 bv = *(const float4*)(g_bias + cbase + 4 * lh);
#pragma unroll
        for (int rg = 0; rg < 4; ++rg) {
            f32x4 acc = {bv.x, bv.y, bv.z, bv.w};
            acc = __builtin_amdgcn_mfma_f32_16x16x32_bf16(A0, Bf[rg][0], acc, 0, 0, 0);
            acc = __builtin_amdgcn_mfma_f32_16x16x32_bf16(A1, Bf[rg][1], acc, 0, 0, 0);
            acc = __builtin_amdgcn_mfma_f32_16x16x32_bf16(A2, Bf[rg][2], acc, 0, 0, 0);
            acc = __builtin_amdgcn_mfma_f32_16x16x32_bf16(A3, Bf[rg][3], acc, 0, 0, 0);
            u32 p0 = (u32)f2b(acc[0]) | ((u32)f2b(acc[1]) << 16);
            u32 p1 = (u32)f2b(acc[2]) | ((u32)f2b(acc[3]) << 16);
            uint2 pv; pv.x = p0; pv.y = p1;
            *(uint2*)(g_xg + (size_t)(m0 + rg * 16 + lr) * G_ + cbase + 4 * lh) = pv;
        }
    }
}

// ---------- K2: recurrence, split-K pairs (512 thr, 8 waves, 2 waves/EU) ----------
// r3/r9/r10-validated skeleton. r11 changes (serial tail only):
//  (a) pair-combine via DPP add (VALU) instead of 4x shfl_xor (DS pipe);
//  (b) h-quant clamp removed (|h| <= 1+2e-7 by construction -> rintf in range).
__global__ __launch_bounds__(512)
__attribute__((amdgpu_waves_per_eu(2, 2)))
void lstm_split(const void* __restrict__ h0, const void* __restrict__ c0) {
    const int mode = g_mode;
    const int t = threadIdx.x;
    const int b = blockIdx.x;
    const int u = t >> 1;
    const int half = t & 1;

    __shared__ __align__(16) u32 h8[2][H_ / 4];  // double-buffered h (i8), 2x256 B

    // --- 32 weight quads into named v4u via asm (validated pattern, waitcnt per block) ---
    v4u W00, W01, W02, W03, W04, W05, W06, W07, W08, W09, W10, W11, W12, W13, W14, W15;
    v4u W16, W17, W18, W19, W20, W21, W22, W23, W24, W25, W26, W27, W28, W29, W30, W31;
    {
        const u32* wp = g_Wi8 + (size_t)t * 128;   // = u*256 + half*128
        asm volatile(
            "global_load_dwordx4 %0, %16, off\n\t"
            "global_load_dwordx4 %1, %16, off offset:16\n\t"
            "global_load_dwordx4 %2, %16, off offset:32\n\t"
            "global_load_dwordx4 %3, %16, off offset:48\n\t"
            "global_load_dwordx4 %4, %16, off offset:64\n\t"
            "global_load_dwordx4 %5, %16, off offset:80\n\t"
            "global_load_dwordx4 %6, %16, off offset:96\n\t"
            "global_load_dwordx4 %7, %16, off offset:112\n\t"
            "global_load_dwordx4 %8, %16, off offset:128\n\t"
            "global_load_dwordx4 %9, %16, off offset:144\n\t"
            "global_load_dwordx4 %10, %16, off offset:160\n\t"
            "global_load_dwordx4 %11, %16, off offset:176\n\t"
            "global_load_dwordx4 %12, %16, off offset:192\n\t"
            "global_load_dwordx4 %13, %16, off offset:208\n\t"
            "global_load_dwordx4 %14, %16, off offset:224\n\t"
            "global_load_dwordx4 %15, %16, off offset:240\n\t"
            "s_waitcnt vmcnt(0)"
            : "=&v"(W00), "=&v"(W01), "=&v"(W02), "=&v"(W03),
              "=&v"(W04), "=&v"(W05), "=&v"(W06), "=&v"(W07),
              "=&v"(W08), "=&v"(W09), "=&v"(W10), "=&v"(W11),
              "=&v"(W12), "=&v"(W13), "=&v"(W14), "=&v"(W15)
            : "v"(wp));
        asm volatile(
            "global_load_dwordx4 %0, %16, off offset:256\n\t"
            "global_load_dwordx4 %1, %16, off offset:272\n\t"
            "global_load_dwordx4 %2, %16, off offset:288\n\t"
            "global_load_dwordx4 %3, %16, off offset:304\n\t"
            "global_load_dwordx4 %4, %16, off offset:320\n\t"
            "global_load_dwordx4 %5, %16, off offset:336\n\t"
            "global_load_dwordx4 %6, %16, off offset:352\n\t"
            "global_load_dwordx4 %7, %16, off offset:368\n\t"
            "global_load_dwordx4 %8, %16, off offset:384\n\t"
            "global_load_dwordx4 %9, %16, off offset:400\n\t"
            "global_load_dwordx4 %10, %16, off offset:416\n\t"
            "global_load_dwordx4 %11, %16, off offset:432\n\t"
            "global_load_dwordx4 %12, %16, off offset:448\n\t"
            "global_load_dwordx4 %13, %16, off offset:464\n\t"
            "global_load_dwordx4 %14, %16, off offset:480\n\t"
            "global_load_dwordx4 %15, %16, off offset:496\n\t"
            "s_waitcnt vmcnt(0)"
            : "=&v"(W16), "=&v"(W17), "=&v"(W18), "=&v"(W19),
              "=&v"(W20), "=&v"(W21), "=&v"(W22), "=&v"(W23),
              "=&v"(W24), "=&v"(W25), "=&v"(W26), "=&v"(W27),
              "=&v"(W28), "=&v"(W29), "=&v"(W30), "=&v"(W31)
            : "v"(wp));
    }

    const float4 wsc4 = *(const float4*)(g_wscale + 4 * u);
    float c_reg = (half == 0) ? ldin(mode, c0, (size_t)b * H_ + u) : 0.0f;

    if (t < H_ / 4) {
        u32 pk = 0;
#pragma unroll
        for (int i = 0; i < 4; ++i) {
            float h = ldin(mode, h0, (size_t)b * H_ + 4 * t + i);
            int q = (int)rintf(fminf(fmaxf(h, -1.0f), 1.0f) * 127.0f);
            pk |= ((u32)(q & 0xff)) << (8 * i);
        }
        h8[0][t] = pk;
    }
    const u16* xp = g_xg + (size_t)b * S_ * G_ + 4 * u;
    float* hsp = g_hs + (size_t)b * S_ * H_ + u;

    // prime rolling prefetch buffer (all lanes load; odd lanes' copies unused but
    // same cache lines -> no extra traffic, no divergence)
    ushort4 xq[4];
#pragma unroll
    for (int e = 0; e < 4; ++e)
        xq[e] = *(const ushort4*)(xp + (size_t)e * G_);

    asm volatile("s_waitcnt lgkmcnt(0)\n\t"
                 "s_barrier" ::: "memory");

#define DOTG(HV, WA, WB, WC, WD)                                              \
            ai = dot4i8(HV.x, WA.x, ai); af = dot4i8(HV.x, WA.y, af);         \
            ag = dot4i8(HV.x, WA.z, ag); ao = dot4i8(HV.x, WA.w, ao);         \
            ai = dot4i8(HV.y, WB.x, ai); af = dot4i8(HV.y, WB.y, af);         \
            ag = dot4i8(HV.y, WB.z, ag); ao = dot4i8(HV.y, WB.w, ao);         \
            ai = dot4i8(HV.z, WC.x, ai); af = dot4i8(HV.z, WC.y, af);         \
            ag = dot4i8(HV.z, WC.z, ag); ao = dot4i8(HV.z, WC.w, ao);         \
            ai = dot4i8(HV.w, WD.x, ai); af = dot4i8(HV.w, WD.y, af);         \
            ag = dot4i8(HV.w, WD.z, ag); ao = dot4i8(HV.w, WD.w, ao);

    for (int s0 = 0; s0 < S_; s0 += 4) {
#pragma unroll
        for (int e = 0; e < 4; ++e) {
            const int s = s0 + e;
            // consume current xq, immediately re-issue for s+4 (rolling prefetch)
            const ushort4 xv = xq[e];
            const int sn = (s + 4 < S_) ? s + 4 : s;
            xq[e] = *(const ushort4*)(xp + (size_t)sn * G_);

            const uint4* hp = (const uint4*)h8[s & 1] + half * 8;
            uint4 h0v = hp[0], h1v = hp[1], h2v = hp[2], h3v = hp[3];
            uint4 h4v = hp[4], h5v = hp[5], h6v = hp[6], h7v = hp[7];

            int ai = 0, af = 0, ag = 0, ao = 0;
            DOTG(h0v, W00, W01, W02, W03)
            DOTG(h1v, W04, W05, W06, W07)
            DOTG(h2v, W08, W09, W10, W11)
            DOTG(h3v, W12, W13, W14, W15)
            DOTG(h4v, W16, W17, W18, W19)
            DOTG(h5v, W20, W21, W22, W23)
            DOTG(h6v, W24, W25, W26, W27)
            DOTG(h7v, W28, W29, W30, W31)

            ai = dppadd1(ai);
            af = dppadd1(af);
            ag = dppadd1(ag);
            ao = dppadd1(ao);

            if (half == 0) {
                float gi = (float)ai * wsc4.x + b2f(xv.x);
                float gf = (float)af * wsc4.y + b2f(xv.y);
                float gg = (float)ag * wsc4.z + b2f(xv.z);
                float go = (float)ao * wsc4.w + b2f(xv.w);
                float ii = fsig(gi);
                float ff = fsig(gf);
                float gv = ftanh(gg);
                float oo = fsig(go);
                c_reg = fmaf(ff, c_reg, ii * gv);
                float h = oo * ftanh(c_reg);
                int q = (int)rintf(h * 127.0f) & 0xff;   // |h|<=1+2e-7 -> in range
                ((u8*)h8[(s + 1) & 1])[u] = (u8)q;   // single-byte publish
                hsp[(size_t)s * H_] = h;             // fire-and-forget
            }
            // LDS ordering only; global loads/stores stay in flight
            asm volatile("s_waitcnt lgkmcnt(0)\n\t"
                         "s_barrier" ::: "memory");
        }
    }
#undef DOTG
}

// ---------- K3: output head — one wave per (s,b), fp32 h (precise math, unchanged) ----------
__global__ __launch_bounds__(256) void head_kernel(const void* __restrict__ Wout,
                                                   const void* __restrict__ bout,
                                                   void* __restrict__ yv) {
    const int mode = g_mode;
    const int t = threadIdx.x;
    const int idx = blockIdx.x * 4 + (t >> 6);   // (s,b) pair
    const int l = t & 63;
    const int s = idx >> 6, b = idx & 63;
    const float* hb = g_hs + ((size_t)b * S_ + s) * H_ + 4 * l;
    float4 hv = *(const float4*)hb;
    float p = hv.x * ldin(mode, Wout, 4 * l + 0)
            + hv.y * ldin(mode, Wout, 4 * l + 1)
            + hv.z * ldin(mode, Wout, 4 * l + 2)
            + hv.w * ldin(mode, Wout, 4 * l + 3);
#pragma unroll
    for (int off = 32; off > 0; off >>= 1) p += __shfl_down(p, off, 64);
    if (l == 0) {
        float yf = sigmoidf_(clamp30(p + ldin(mode, bout, 0)));
        if (mode) ((float*)yv)[(size_t)s * B_ + b] = yf;
        else      ((u16*)yv)[(size_t)s * B_ + b] = f2b(yf);
    }
}

extern "C" void kernel_launch(void* const* d_in, const int* in_sizes, int n_in,
                              void* d_out, int out_size, void* d_ws, size_t ws_size,
                              hipStream_t stream) {
    const void* pw   = d_in[0];   // [B,S,50]
    const void* Wemb = d_in[1];   // [E,50]
    const void* bemb = d_in[2];   // [E]
    const void* Wih  = d_in[3];   // [G,E]
    const void* Whh  = d_in[4];   // [G,H]
    const void* bih  = d_in[5];   // [G]
    const void* bhh  = d_in[6];   // [G]
    const void* Wout = d_in[7];   // [1,H]
    const void* bout = d_in[8];   // [1]
    const void* h0   = d_in[9];   // [B,H]
    const void* c0   = d_in[10];  // [B,H]
    void* y = d_out;              // [S,B]
    (void)d_ws; (void)ws_size;

    sniff_kernel<<<1, 1, 0, stream>>>((const u16*)Wemb);
    prep_wa<<<(E_ * G_) / 256, 256, 0, stream>>>(Wih);
    prep_wi8<<<G_ / 256, 256, 0, stream>>>(Whh, bih, bhh);
    xg_mfma<<<(B_ * S_) / 64, 256, 0, stream>>>(pw, Wemb, bemb);
    lstm_split<<<B_, 512, 0, stream>>>(h0, c0);
    head_kernel<<<(S_ * B_) / 4, 256, 0, stream>>>(Wout, bout, y);
}